// Round 1
// baseline (6183.527 us; speedup 1.0000x reference)
//
#include <hip/hip_runtime.h>
#include <math.h>

// ---------------------------------------------------------------------------
// ConvAttBlock (RegionViT R2L block) — fp32 correctness-first implementation.
// B=64, CIN=192, C=384, NH=12, HD=32, HID=1536, WS=7, NB=2.
// Token layout XT: [1024 windows * 50 tokens, 384]; window w = b*16 + (hk*4+wk),
// token 0 = cls, token 1+kh*7+kw = patch within window.
// ---------------------------------------------------------------------------

__device__ __forceinline__ float gelu_f(float x) {
  return 0.5f * x * (1.0f + erff(x * 0.70710678118654752440f));
}

// ---- LN over 192 channels (NCHW input) + GELU -> channels-last temp --------
__global__ __launch_bounds__(256) void k_ln_gelu_c192(
    const float* __restrict__ x, float* __restrict__ t,
    const float* __restrict__ g, const float* __restrict__ b,
    int HW, int npos)
{
  int wid = threadIdx.x >> 6, lane = threadIdx.x & 63;
  int pos = blockIdx.x * 4 + wid;
  if (pos >= npos) return;
  int bi = pos / HW, p = pos - bi * HW;
  const float* xp = x + (long)bi * 192 * HW + p;
  float v0 = xp[(long)(lane      ) * HW];
  float v1 = xp[(long)(lane +  64) * HW];
  float v2 = xp[(long)(lane + 128) * HW];
  float s  = v0 + v1 + v2;
  float sq = v0*v0 + v1*v1 + v2*v2;
  #pragma unroll
  for (int o = 1; o < 64; o <<= 1) { s += __shfl_xor(s, o); sq += __shfl_xor(sq, o); }
  float mean = s * (1.0f/192.0f);
  float var  = sq * (1.0f/192.0f) - mean*mean;
  float rstd = rsqrtf(var + 1e-5f);
  float* tp = t + (long)pos * 192;
  int c0 = lane, c1 = lane + 64, c2 = lane + 128;
  tp[c0] = gelu_f((v0-mean)*rstd*g[c0] + b[c0]);
  tp[c1] = gelu_f((v1-mean)*rstd*g[c1] + b[c1]);
  tp[c2] = gelu_f((v2-mean)*rstd*g[c2] + b[c2]);
}

// ---- depthwise stride-2 conv (3x3, pad 1, 192->384, 2 out per in chan) -----
// reads channels-last temp, writes directly into token layout XT
__global__ __launch_bounds__(384) void k_dwconv(
    const float* __restrict__ t, const float* __restrict__ w,
    const float* __restrict__ bias, float* __restrict__ XT,
    int Hin, int Win, int Hout, int Wout, int isCls)
{
  int o = threadIdx.x;            // output channel 0..383
  int blk = blockIdx.x;
  int b = blk / Hout, oh = blk - b * Hout;
  int ic = o >> 1;
  float wr[9];
  #pragma unroll
  for (int q = 0; q < 9; ++q) wr[q] = w[q * 384 + o];
  float bo = bias[o];
  const float* tb = t + (long)b * Hin * Win * 192;
  for (int ow = 0; ow < Wout; ++ow) {
    float acc = bo;
    #pragma unroll
    for (int ky = 0; ky < 3; ++ky) {
      int ih = 2*oh - 1 + ky;
      if (ih < 0 || ih >= Hin) continue;
      #pragma unroll
      for (int kx = 0; kx < 3; ++kx) {
        int iw = 2*ow - 1 + kx;
        if (iw < 0 || iw >= Win) continue;
        acc += wr[ky*3+kx] * tb[((long)ih * Win + iw) * 192 + ic];
      }
    }
    int row;
    if (isCls) row = (b * 16 + oh * Wout + ow) * 50;
    else       row = (b * 16 + (oh/7)*4 + (ow/7)) * 50 + 1 + (oh%7)*7 + (ow%7);
    XT[(long)row * 384 + o] = acc;
  }
}

// ---- LayerNorm over C=384 (one wave per row, strided rows supported) -------
__global__ __launch_bounds__(256) void k_ln384(
    const float* __restrict__ in, long istride,
    float* __restrict__ out, long ostride,
    const float* __restrict__ g, const float* __restrict__ b, int rows)
{
  int wid = threadIdx.x >> 6, lane = threadIdx.x & 63;
  int r = blockIdx.x * 4 + wid;
  if (r >= rows) return;
  const float* ip = in + (long)r * istride;
  float x[6]; float s = 0.f, sq = 0.f;
  #pragma unroll
  for (int j = 0; j < 6; ++j) {
    x[j] = ip[lane + 64*j];
    s += x[j]; sq += x[j]*x[j];
  }
  #pragma unroll
  for (int o = 1; o < 64; o <<= 1) { s += __shfl_xor(s, o); sq += __shfl_xor(sq, o); }
  float mean = s * (1.0f/384.0f);
  float var  = sq * (1.0f/384.0f) - mean*mean;
  float rstd = rsqrtf(var + 1e-5f);
  float* op = out + (long)r * ostride;
  #pragma unroll
  for (int j = 0; j < 6; ++j) {
    int c = lane + 64*j;
    op[c] = (x[j]-mean)*rstd*g[c] + b[c];
  }
}

// ---- fp32 tiled GEMM: C[M,N] = A[M,K] @ B[K,N] + bias (opt gelu / accum) ---
// 64x64 tile, BK=16, 256 threads, 4x4 micro-tile. All dims divisible.
__global__ __launch_bounds__(256) void k_gemm(
    const float* __restrict__ A, const float* __restrict__ B,
    const float* __restrict__ bias, float* __restrict__ C,
    int K, int lda, int ldb, int ldc, int flags /*1=accum, 2=gelu*/)
{
  __shared__ float As[16][68];
  __shared__ float Bs[16][68];
  int tid = threadIdx.x;
  int m0 = blockIdx.y * 64, n0 = blockIdx.x * 64;
  int tx = tid & 15, ty = tid >> 4;
  int arow = tid >> 2, akq = (tid & 3) << 2;
  int brow = tid >> 4, bcol = (tid & 15) << 2;
  float acc[4][4] = {{0.f}};
  const float* Ap = A + (long)(m0 + arow) * lda + akq;
  const float* Bp = B + (long)brow * ldb + n0 + bcol;
  for (int k0 = 0; k0 < K; k0 += 16) {
    float4 av = *(const float4*)(Ap + k0);
    float4 bv = *(const float4*)(Bp + (long)k0 * ldb);
    As[akq+0][arow] = av.x;
    As[akq+1][arow] = av.y;
    As[akq+2][arow] = av.z;
    As[akq+3][arow] = av.w;
    *(float4*)&Bs[brow][bcol] = bv;
    __syncthreads();
    #pragma unroll
    for (int kk = 0; kk < 16; ++kk) {
      float4 a  = *(const float4*)&As[kk][ty << 2];
      float4 bb = *(const float4*)&Bs[kk][tx << 2];
      acc[0][0] += a.x*bb.x; acc[0][1] += a.x*bb.y; acc[0][2] += a.x*bb.z; acc[0][3] += a.x*bb.w;
      acc[1][0] += a.y*bb.x; acc[1][1] += a.y*bb.y; acc[1][2] += a.y*bb.z; acc[1][3] += a.y*bb.w;
      acc[2][0] += a.z*bb.x; acc[2][1] += a.z*bb.y; acc[2][2] += a.z*bb.z; acc[2][3] += a.z*bb.w;
      acc[3][0] += a.w*bb.x; acc[3][1] += a.w*bb.y; acc[3][2] += a.w*bb.z; acc[3][3] += a.w*bb.w;
    }
    __syncthreads();
  }
  #pragma unroll
  for (int i = 0; i < 4; ++i) {
    int m = m0 + (ty << 2) + i;
    float* Cp = C + (long)m * ldc + n0 + (tx << 2);
    #pragma unroll
    for (int j = 0; j < 4; ++j) {
      float v = acc[i][j] + bias[n0 + (tx << 2) + j];
      if (flags & 2) v = gelu_f(v);
      if (flags & 1) v += Cp[j];
      Cp[j] = v;
    }
  }
}

// ---- fused attention per (group, head): QK^T + bias -> softmax -> PV -------
// qkv rows [group*N .. group*N+N), cols: q h*32, k 384+h*32, v 768+h*32
__global__ __launch_bounds__(256) void k_attn(
    const float* __restrict__ qkv, float* __restrict__ o,
    const float* __restrict__ relpos, int N, int ld, int ldo)
{
  int g = blockIdx.x / 12, h = blockIdx.x % 12;
  __shared__ float q[50][33], k[50][33], v[50][33];
  __shared__ float S[50][51];
  __shared__ float rmax[50], rsum[50];
  int tid = threadIdx.x;
  int row0 = g * N;
  const float* base = qkv + (long)row0 * ld + h * 32;
  for (int e = tid; e < N * 32; e += 256) {
    int i = e >> 5, d = e & 31;
    long off = (long)i * ld + d;
    q[i][d] = base[off];
    k[i][d] = base[off + 384];
    v[i][d] = base[off + 768];
  }
  __syncthreads();
  const float scale = 0.17677669529663687f;  // 32^-0.5
  const float* rph = relpos ? relpos + h * 169 : (const float*)0;
  for (int e = tid; e < N * N; e += 256) {
    int i = e / N, j = e - i * N;
    float acc = 0.f;
    #pragma unroll
    for (int d = 0; d < 32; ++d) acc += q[i][d] * k[j][d];
    acc *= scale;
    if (rph && i > 0 && j > 0) {
      int qi = i - 1, ki = j - 1;
      int qr = qi / 7, qc = qi - qr * 7;
      int kr = ki / 7, kc = ki - kr * 7;
      acc += rph[(qr - kr + 6) * 13 + (qc - kc + 6)];
    }
    S[i][j] = acc;
  }
  __syncthreads();
  if (tid < N) {
    float m = -1e30f;
    for (int j = 0; j < N; ++j) m = fmaxf(m, S[tid][j]);
    rmax[tid] = m;
  }
  __syncthreads();
  for (int e = tid; e < N * N; e += 256) {
    int i = e / N, j = e - i * N;
    S[i][j] = expf(S[i][j] - rmax[i]);
  }
  __syncthreads();
  if (tid < N) {
    float s = 0.f;
    for (int j = 0; j < N; ++j) s += S[tid][j];
    rsum[tid] = 1.0f / s;
  }
  __syncthreads();
  for (int e = tid; e < N * 32; e += 256) {
    int i = e >> 5, d = e & 31;
    float acc = 0.f;
    for (int j = 0; j < N; ++j) acc += S[i][j] * v[j][d];
    o[(long)(row0 + i) * ldo + h * 32 + d] = acc * rsum[i];
  }
}

// ---- fold token layout back to NCHW outputs --------------------------------
__global__ __launch_bounds__(256) void k_fold(
    const float* __restrict__ XT, float* __restrict__ out)
{
  long idx = (long)blockIdx.x * 256 + threadIdx.x;
  if (idx < 393216) {  // cls_out [64,384,4,4]
    int b = (int)(idx / (384*16));
    int rem = (int)(idx % (384*16));
    int c = rem / 16, p = rem % 16;
    out[idx] = XT[((long)(b*16 + p) * 50) * 384 + c];
  } else {             // patch_out [64,384,28,28]
    long j = idx - 393216;
    int b = (int)(j / (384*784));
    int rem = (int)(j % (384*784));
    int c = rem / 784, p = rem % 784;
    int oh = p / 28, ow = p % 28;
    int row = (b*16 + (oh/7)*4 + ow/7) * 50 + 1 + (oh%7)*7 + (ow%7);
    out[idx] = XT[(long)row * 384 + c];
  }
}

extern "C" void kernel_launch(void* const* d_in, const int* in_sizes, int n_in,
                              void* d_out, int out_size, void* d_ws, size_t ws_size,
                              hipStream_t stream)
{
  const float* cls_in   = (const float*)d_in[0];
  const float* patch_in = (const float*)d_in[1];
  const float* pg   = (const float*)d_in[2];
  const float* pb   = (const float*)d_in[3];
  const float* cw   = (const float*)d_in[4];
  const float* cb   = (const float*)d_in[5];
  const float* n0g  = (const float*)d_in[6];
  const float* n0b  = (const float*)d_in[7];
  const float* n1g  = (const float*)d_in[8];
  const float* n1b  = (const float*)d_in[9];
  const float* n2g  = (const float*)d_in[10];
  const float* n2b  = (const float*)d_in[11];
  const float* qkvw = (const float*)d_in[12];
  const float* qkvb = (const float*)d_in[13];
  const float* apw  = (const float*)d_in[14];
  const float* apb  = (const float*)d_in[15];
  const float* rp   = (const float*)d_in[16];
  const float* f1w  = (const float*)d_in[17];
  const float* f1b  = (const float*)d_in[18];
  const float* f2w  = (const float*)d_in[19];
  const float* f2b  = (const float*)d_in[20];
  float* out = (float*)d_out;

  // workspace layout (floats):
  //   XT  [51200*384]           tokens (persistent)
  //   LN  [51200*384]           layernorm output
  //   SC  [78643200]            qkv (58,982,400) | O (19,660,800)  /  mlp hidden  /  conv temp
  float* XT = (float*)d_ws;
  float* LN = XT + 19660800;
  float* SC = LN + 19660800;
  float* OB = SC + 58982400;
  float* tP = SC;                 // patch LN+GELU temp [64*56*56*192]
  float* tC = SC + 38535168;      // cls temp [64*8*8*192]

  // --- projection ---
  k_ln_gelu_c192<<<50176, 256, 0, stream>>>(patch_in, tP, pg, pb, 3136, 200704);
  k_ln_gelu_c192<<<1024,  256, 0, stream>>>(cls_in,   tC, pg, pb, 64,   4096);
  k_dwconv<<<1792, 384, 0, stream>>>(tP, cw, cb, XT, 56, 56, 28, 28, 0);
  k_dwconv<<<256,  384, 0, stream>>>(tC, cw, cb, XT, 8, 8, 4, 4, 1);

  for (int i = 0; i < 2; ++i) {
    const float* qw  = qkvw + (long)i*384*1152;
    const float* qb  = qkvb + i*1152;
    const float* aw  = apw  + (long)i*384*384;
    const float* ab  = apb  + i*384;
    const float* rpi = rp   + (long)i*12*169;

    // regional (cls) attention across 16 windows per image
    k_ln384<<<256, 256, 0, stream>>>(XT, 19200, LN, 384, n0g + i*384, n0b + i*384, 1024);
    k_gemm<<<dim3(18,16), 256, 0, stream>>>(LN, qw, qb, SC, 384, 384, 1152, 1152, 0);
    k_attn<<<768, 256, 0, stream>>>(SC, OB, (const float*)0, 16, 1152, 384);
    k_gemm<<<dim3(6,16), 256, 0, stream>>>(OB, aw, ab, XT, 384, 384, 384, 19200, 1);

    // local attention within each window (50 tokens, rel-pos bias)
    k_ln384<<<12800, 256, 0, stream>>>(XT, 384, LN, 384, n1g + i*384, n1b + i*384, 51200);
    k_gemm<<<dim3(18,800), 256, 0, stream>>>(LN, qw, qb, SC, 384, 384, 1152, 1152, 0);
    k_attn<<<12288, 256, 0, stream>>>(SC, OB, rpi, 50, 1152, 384);
    k_gemm<<<dim3(6,800), 256, 0, stream>>>(OB, aw, ab, XT, 384, 384, 384, 384, 1);

    // MLP
    k_ln384<<<12800, 256, 0, stream>>>(XT, 384, LN, 384, n2g + i*384, n2b + i*384, 51200);
    k_gemm<<<dim3(24,800), 256, 0, stream>>>(LN, f1w + (long)i*384*1536, f1b + i*1536,
                                             SC, 384, 384, 1536, 1536, 2);
    k_gemm<<<dim3(6,800), 256, 0, stream>>>(SC, f2w + (long)i*1536*384, f2b + i*384,
                                            XT, 1536, 1536, 384, 384, 1);
  }

  k_fold<<<76800, 256, 0, stream>>>(XT, out);
}

// Round 2
// 2447.294 us; speedup vs baseline: 2.5267x; 2.5267x over previous
//
#include <hip/hip_runtime.h>
#include <hip/hip_bf16.h>
#include <math.h>

// ---------------------------------------------------------------------------
// ConvAttBlock (RegionViT R2L block) — bf16 MFMA GEMMs + restructured attention.
// B=64, CIN=192, C=384, NH=12, HD=32, HID=1536, WS=7, NB=2.
// Token layout XT: [1024 windows * 50 tokens, 384] fp32 (residual stream).
// ---------------------------------------------------------------------------

typedef __attribute__((ext_vector_type(8))) short short8;   // 8 bf16 (4 VGPR)
typedef __attribute__((ext_vector_type(4))) float f32x4;

__device__ __forceinline__ float gelu_f(float x) {
  return 0.5f * x * (1.0f + erff(x * 0.70710678118654752440f));
}

// ---- LN over 192 channels (NCHW input) + GELU -> channels-last temp --------
__global__ __launch_bounds__(256) void k_ln_gelu_c192(
    const float* __restrict__ x, float* __restrict__ t,
    const float* __restrict__ g, const float* __restrict__ b,
    int HW, int npos)
{
  int wid = threadIdx.x >> 6, lane = threadIdx.x & 63;
  int pos = blockIdx.x * 4 + wid;
  if (pos >= npos) return;
  int bi = pos / HW, p = pos - bi * HW;
  const float* xp = x + (long)bi * 192 * HW + p;
  float v0 = xp[(long)(lane      ) * HW];
  float v1 = xp[(long)(lane +  64) * HW];
  float v2 = xp[(long)(lane + 128) * HW];
  float s  = v0 + v1 + v2;
  float sq = v0*v0 + v1*v1 + v2*v2;
  #pragma unroll
  for (int o = 1; o < 64; o <<= 1) { s += __shfl_xor(s, o); sq += __shfl_xor(sq, o); }
  float mean = s * (1.0f/192.0f);
  float var  = sq * (1.0f/192.0f) - mean*mean;
  float rstd = rsqrtf(var + 1e-5f);
  float* tp = t + (long)pos * 192;
  int c0 = lane, c1 = lane + 64, c2 = lane + 128;
  tp[c0] = gelu_f((v0-mean)*rstd*g[c0] + b[c0]);
  tp[c1] = gelu_f((v1-mean)*rstd*g[c1] + b[c1]);
  tp[c2] = gelu_f((v2-mean)*rstd*g[c2] + b[c2]);
}

// ---- depthwise stride-2 conv (3x3, pad 1, 192->384, 2 out per in chan) -----
__global__ __launch_bounds__(384) void k_dwconv(
    const float* __restrict__ t, const float* __restrict__ w,
    const float* __restrict__ bias, float* __restrict__ XT,
    int Hin, int Win, int Hout, int Wout, int isCls)
{
  int o = threadIdx.x;            // output channel 0..383
  int blk = blockIdx.x;
  int b = blk / Hout, oh = blk - b * Hout;
  int ic = o >> 1;
  float wr[9];
  #pragma unroll
  for (int q = 0; q < 9; ++q) wr[q] = w[q * 384 + o];
  float bo = bias[o];
  const float* tb = t + (long)b * Hin * Win * 192;
  for (int ow = 0; ow < Wout; ++ow) {
    float acc = bo;
    #pragma unroll
    for (int ky = 0; ky < 3; ++ky) {
      int ih = 2*oh - 1 + ky;
      if (ih < 0 || ih >= Hin) continue;
      #pragma unroll
      for (int kx = 0; kx < 3; ++kx) {
        int iw = 2*ow - 1 + kx;
        if (iw < 0 || iw >= Win) continue;
        acc += wr[ky*3+kx] * tb[((long)ih * Win + iw) * 192 + ic];
      }
    }
    int row;
    if (isCls) row = (b * 16 + oh * Wout + ow) * 50;
    else       row = (b * 16 + (oh/7)*4 + (ow/7)) * 50 + 1 + (oh%7)*7 + (ow%7);
    XT[(long)row * 384 + o] = acc;
  }
}

// ---- LayerNorm over C=384, fp32 in (strided rows ok) -> bf16 out -----------
__global__ __launch_bounds__(256) void k_ln384(
    const float* __restrict__ in, long istride,
    __hip_bfloat16* __restrict__ out, long ostride,
    const float* __restrict__ g, const float* __restrict__ b, int rows)
{
  int wid = threadIdx.x >> 6, lane = threadIdx.x & 63;
  int r = blockIdx.x * 4 + wid;
  if (r >= rows) return;
  const float* ip = in + (long)r * istride;
  float x[6]; float s = 0.f, sq = 0.f;
  #pragma unroll
  for (int j = 0; j < 6; ++j) {
    x[j] = ip[lane + 64*j];
    s += x[j]; sq += x[j]*x[j];
  }
  #pragma unroll
  for (int o = 1; o < 64; o <<= 1) { s += __shfl_xor(s, o); sq += __shfl_xor(sq, o); }
  float mean = s * (1.0f/384.0f);
  float var  = sq * (1.0f/384.0f) - mean*mean;
  float rstd = rsqrtf(var + 1e-5f);
  __hip_bfloat16* op = out + (long)r * ostride;
  #pragma unroll
  for (int j = 0; j < 6; ++j) {
    int c = lane + 64*j;
    op[c] = __float2bfloat16((x[j]-mean)*rstd*g[c] + b[c]);
  }
}

// ---- weight transpose + fp32->bf16: W[K][N] -> Wt[N][K] --------------------
__global__ __launch_bounds__(256) void k_wT(
    const float* __restrict__ W, __hip_bfloat16* __restrict__ Wt, int K, int N)
{
  __shared__ ushort t[64][65];
  int n0 = blockIdx.x * 64, k0 = blockIdx.y * 64;
  int c = threadIdx.x & 63, r4 = threadIdx.x >> 6;
  #pragma unroll
  for (int s = 0; s < 16; ++s) {
    int k = r4 + s*4;
    __hip_bfloat16 h = __float2bfloat16(W[(long)(k0+k)*N + n0 + c]);
    t[k][c] = *(ushort*)&h;
  }
  __syncthreads();
  #pragma unroll
  for (int s = 0; s < 16; ++s) {
    int n = r4 + s*4;
    ushort u = t[c][n];
    Wt[(long)(n0+n)*K + k0 + c] = *(__hip_bfloat16*)&u;
  }
}

// ---- bf16 MFMA GEMM: C[M,N] = A[M,K]·Bt[N,K]^T + bias ----------------------
// 128x128 tile, BK=32, 256 thr (4 waves 2x2), mfma_f32_16x16x32_bf16.
// flags: 1=accum into fp32 C, 2=gelu, 4=bf16 output (else fp32)
__global__ __launch_bounds__(256) void k_gemm_bf16(
    const ushort* __restrict__ A, const ushort* __restrict__ Bt,
    const float* __restrict__ bias, void* __restrict__ Cv,
    int K, int lda, int ldbt, int ldc, int flags)
{
  __shared__ ushort As[128*32];
  __shared__ ushort Bs[128*32];
  int tid = threadIdx.x;
  int w = tid >> 6, lane = tid & 63;
  int m0 = blockIdx.y * 128, n0 = blockIdx.x * 128;
  int wr = (w >> 1) * 64, wc = (w & 1) * 64;
  f32x4 acc[4][4] = {};

  int sRow = lane >> 2;            // 0..15 within 16-row chunk
  int sCol = (lane & 3) * 8;       // k element offset (8 bf16 = 16B)
  const ushort* Abase = A  + (long)m0 * lda + sCol;
  const ushort* Bbase = Bt + (long)n0 * ldbt + sCol;

  for (int k0 = 0; k0 < K; k0 += 32) {
    #pragma unroll
    for (int p = 0; p < 2; ++p) {
      int chunk = w + 4*p;             // 0..7, wave-uniform
      int row = chunk * 16 + sRow;
      __builtin_amdgcn_global_load_lds(
        (const __attribute__((address_space(1))) void*)(Abase + (long)row*lda + k0),
        (__attribute__((address_space(3))) void*)(As + chunk*512), 16, 0, 0);
      __builtin_amdgcn_global_load_lds(
        (const __attribute__((address_space(1))) void*)(Bbase + (long)row*ldbt + k0),
        (__attribute__((address_space(3))) void*)(Bs + chunk*512), 16, 0, 0);
    }
    __syncthreads();   // drains vmcnt + lgkmcnt

    short8 af[4], bf[4];
    int kq = (lane >> 4) * 8;
    int fr = lane & 15;
    #pragma unroll
    for (int mi = 0; mi < 4; ++mi)
      af[mi] = *(const short8*)(As + (wr + mi*16 + fr)*32 + kq);
    #pragma unroll
    for (int ni = 0; ni < 4; ++ni)
      bf[ni] = *(const short8*)(Bs + (wc + ni*16 + fr)*32 + kq);
    #pragma unroll
    for (int mi = 0; mi < 4; ++mi)
      #pragma unroll
      for (int ni = 0; ni < 4; ++ni)
        acc[mi][ni] = __builtin_amdgcn_mfma_f32_16x16x32_bf16(af[mi], bf[ni], acc[mi][ni], 0, 0, 0);
    __syncthreads();   // protect LDS before next stage
  }

  // epilogue: C/D layout col=lane&15, row=(lane>>4)*4+reg
  int colq = lane & 15, rowq = (lane >> 4) * 4;
  #pragma unroll
  for (int mi = 0; mi < 4; ++mi) {
    #pragma unroll
    for (int ni = 0; ni < 4; ++ni) {
      int col = n0 + wc + ni*16 + colq;
      float bv = bias[col];
      #pragma unroll
      for (int r = 0; r < 4; ++r) {
        int m = m0 + wr + mi*16 + rowq + r;
        float v = acc[mi][ni][r] + bv;
        if (flags & 2) v = gelu_f(v);
        if (flags & 4) {
          ((__hip_bfloat16*)Cv)[(long)m*ldc + col] = __float2bfloat16(v);
        } else {
          float* Cp = (float*)Cv + (long)m*ldc + col;
          float o = v;
          if (flags & 1) o += *Cp;
          *Cp = o;
        }
      }
    }
  }
}

// ---- fused attention per (group, head): QK^T + bias -> softmax -> PV -------
// qkv fp32 rows [g*N .. g*N+N), cols: q h*32, k 384+h*32, v 768+h*32; out bf16
__global__ __launch_bounds__(256) void k_attn2(
    const float* __restrict__ qkv, __hip_bfloat16* __restrict__ o,
    const float* __restrict__ relpos, int N, int ld, int ldo)
{
  int g = blockIdx.x / 12, h = blockIdx.x % 12;
  __shared__ float q[50][36];
  __shared__ float kv[50][36];    // k during QK, v during PV
  __shared__ float S[50][52];
  __shared__ float rsum[64];
  int tid = threadIdx.x;
  int row0 = g * N;
  const float* base = qkv + (long)row0 * ld + h * 32;

  for (int e = tid; e < N * 32; e += 256) {
    int i = e >> 5, d = e & 31;
    long off = (long)i * ld + d;
    q[i][d]  = base[off];
    kv[i][d] = base[off + 384];
  }
  __syncthreads();

  const float scale = 0.17677669529663687f;  // 32^-0.5
  const float* rph = relpos ? relpos + h * 169 : (const float*)0;
  for (int e = tid; e < N * N; e += 256) {
    int i = e / N, j = e - i * N;
    const float4* qp = (const float4*)q[i];
    const float4* kp = (const float4*)kv[j];
    float ax = 0.f, ay = 0.f, az = 0.f, aw = 0.f;
    #pragma unroll
    for (int d4 = 0; d4 < 8; ++d4) {
      float4 a = qp[d4], b = kp[d4];
      ax += a.x*b.x; ay += a.y*b.y; az += a.z*b.z; aw += a.w*b.w;
    }
    float acc = ((ax+ay)+(az+aw)) * scale;
    if (rph && i > 0 && j > 0) {
      int qi = i - 1, ki = j - 1;
      int qr = qi / 7, qc = qi - qr * 7;
      int kr = ki / 7, kc = ki - kr * 7;
      acc += rph[(qr - kr + 6) * 13 + (qc - kc + 6)];
    }
    S[i][j] = acc;
  }
  __syncthreads();

  // overwrite kv with V (QK done); issue loads before softmax to hide latency
  for (int e = tid; e < N * 32; e += 256) {
    int i = e >> 5, d = e & 31;
    kv[i][d] = base[(long)i * ld + d + 768];
  }
  // wave-parallel softmax: one row per wave-iteration
  int wid = tid >> 6, lane = tid & 63;
  for (int r = wid; r < N; r += 4) {
    float v = (lane < N) ? S[r][lane] : -1e30f;
    float m = v;
    #pragma unroll
    for (int o2 = 32; o2 > 0; o2 >>= 1) m = fmaxf(m, __shfl_xor(m, o2));
    float e = (lane < N) ? __expf(v - m) : 0.f;
    float s = e;
    #pragma unroll
    for (int o2 = 32; o2 > 0; o2 >>= 1) s += __shfl_xor(s, o2);
    if (lane < N) S[r][lane] = e;
    if (lane == 0) rsum[r] = 1.0f / s;
  }
  __syncthreads();

  for (int u = tid; u < N * 8; u += 256) {
    int i = u >> 3, d4 = u & 7;
    float ax = 0.f, ay = 0.f, az = 0.f, aw = 0.f;
    for (int j = 0; j < N; ++j) {
      float p = S[i][j];
      float4 vv = *(const float4*)&kv[j][d4*4];
      ax += p*vv.x; ay += p*vv.y; az += p*vv.z; aw += p*vv.w;
    }
    float rs = rsum[i];
    __hip_bfloat16* op = o + (long)(row0 + i) * ldo + h*32 + d4*4;
    op[0] = __float2bfloat16(ax * rs);
    op[1] = __float2bfloat16(ay * rs);
    op[2] = __float2bfloat16(az * rs);
    op[3] = __float2bfloat16(aw * rs);
  }
}

// ---- fold token layout back to NCHW outputs --------------------------------
__global__ __launch_bounds__(256) void k_fold(
    const float* __restrict__ XT, float* __restrict__ out)
{
  long idx = (long)blockIdx.x * 256 + threadIdx.x;
  if (idx < 393216) {  // cls_out [64,384,4,4]
    int b = (int)(idx / (384*16));
    int rem = (int)(idx % (384*16));
    int c = rem / 16, p = rem % 16;
    out[idx] = XT[((long)(b*16 + p) * 50) * 384 + c];
  } else {             // patch_out [64,384,28,28]
    long j = idx - 393216;
    int b = (int)(j / (384*784));
    int rem = (int)(j % (384*784));
    int c = rem / 784, p = rem % 784;
    int oh = p / 28, ow = p % 28;
    int row = (b*16 + (oh/7)*4 + ow/7) * 50 + 1 + (oh%7)*7 + (ow%7);
    out[idx] = XT[(long)row * 384 + c];
  }
}

extern "C" void kernel_launch(void* const* d_in, const int* in_sizes, int n_in,
                              void* d_out, int out_size, void* d_ws, size_t ws_size,
                              hipStream_t stream)
{
  const float* cls_in   = (const float*)d_in[0];
  const float* patch_in = (const float*)d_in[1];
  const float* pg   = (const float*)d_in[2];
  const float* pb   = (const float*)d_in[3];
  const float* cw   = (const float*)d_in[4];
  const float* cb   = (const float*)d_in[5];
  const float* n0g  = (const float*)d_in[6];
  const float* n0b  = (const float*)d_in[7];
  const float* n1g  = (const float*)d_in[8];
  const float* n1b  = (const float*)d_in[9];
  const float* n2g  = (const float*)d_in[10];
  const float* n2b  = (const float*)d_in[11];
  const float* qkvw = (const float*)d_in[12];
  const float* qkvb = (const float*)d_in[13];
  const float* apw  = (const float*)d_in[14];
  const float* apb  = (const float*)d_in[15];
  const float* rp   = (const float*)d_in[16];
  const float* f1w  = (const float*)d_in[17];
  const float* f1b  = (const float*)d_in[18];
  const float* f2w  = (const float*)d_in[19];
  const float* f2b  = (const float*)d_in[20];
  float* out = (float*)d_out;

  // workspace (bytes): XT f32 78.6M | LN bf16 39.3M | SC f32 236M | OB bf16 39.3M | WT bf16 7.1M
  float*          XT = (float*)d_ws;
  __hip_bfloat16* LN = (__hip_bfloat16*)(XT + 19660800);
  float*          SC = (float*)((char*)LN + 39321600);
  __hip_bfloat16* OB = (__hip_bfloat16*)(SC + 58982400);
  __hip_bfloat16* WT = (__hip_bfloat16*)((char*)OB + 39321600);
  float* tP = SC;                 // conv temps alias SC
  float* tC = SC + 38535168;

  // --- projection ---
  k_ln_gelu_c192<<<50176, 256, 0, stream>>>(patch_in, tP, pg, pb, 3136, 200704);
  k_ln_gelu_c192<<<1024,  256, 0, stream>>>(cls_in,   tC, pg, pb, 64,   4096);
  k_dwconv<<<1792, 384, 0, stream>>>(tP, cw, cb, XT, 56, 56, 28, 28, 0);
  k_dwconv<<<256,  384, 0, stream>>>(tC, cw, cb, XT, 8, 8, 4, 4, 1);

  // --- weight transpose/convert (per block: qkvT|apT|fc1T|fc2T) ---
  for (int i = 0; i < 2; ++i) {
    __hip_bfloat16* wb = WT + (long)i * 1769472;
    k_wT<<<dim3(18,6),  256, 0, stream>>>(qkvw + (long)i*442368, wb,           384, 1152);
    k_wT<<<dim3(6,6),   256, 0, stream>>>(apw  + (long)i*147456, wb + 442368,  384, 384);
    k_wT<<<dim3(24,6),  256, 0, stream>>>(f1w  + (long)i*589824, wb + 589824,  384, 1536);
    k_wT<<<dim3(6,24),  256, 0, stream>>>(f2w  + (long)i*589824, wb + 1179648, 1536, 384);
  }

  for (int i = 0; i < 2; ++i) {
    __hip_bfloat16* wb = WT + (long)i * 1769472;
    const ushort* qwT  = (const ushort*)(wb);
    const ushort* apT  = (const ushort*)(wb + 442368);
    const ushort* f1T  = (const ushort*)(wb + 589824);
    const ushort* f2T  = (const ushort*)(wb + 1179648);
    const float* qb  = qkvb + i*1152;
    const float* ab  = apb  + i*384;
    const float* rpi = rp   + (long)i*12*169;

    // regional (cls) attention across 16 windows per image
    k_ln384<<<256, 256, 0, stream>>>(XT, 19200, LN, 384, n0g + i*384, n0b + i*384, 1024);
    k_gemm_bf16<<<dim3(9,8), 256, 0, stream>>>((const ushort*)LN, qwT, qb, SC, 384, 384, 384, 1152, 0);
    k_attn2<<<768, 256, 0, stream>>>(SC, OB, (const float*)0, 16, 1152, 384);
    k_gemm_bf16<<<dim3(3,8), 256, 0, stream>>>((const ushort*)OB, apT, ab, XT, 384, 384, 384, 19200, 1);

    // local attention within each window (50 tokens, rel-pos bias)
    k_ln384<<<12800, 256, 0, stream>>>(XT, 384, LN, 384, n1g + i*384, n1b + i*384, 51200);
    k_gemm_bf16<<<dim3(9,400), 256, 0, stream>>>((const ushort*)LN, qwT, qb, SC, 384, 384, 384, 1152, 0);
    k_attn2<<<12288, 256, 0, stream>>>(SC, OB, rpi, 50, 1152, 384);
    k_gemm_bf16<<<dim3(3,400), 256, 0, stream>>>((const ushort*)OB, apT, ab, XT, 384, 384, 384, 384, 1);

    // MLP
    k_ln384<<<12800, 256, 0, stream>>>(XT, 384, LN, 384, n2g + i*384, n2b + i*384, 51200);
    k_gemm_bf16<<<dim3(12,400), 256, 0, stream>>>((const ushort*)LN, f1T, f1b + i*1536,
                                                  SC, 384, 384, 384, 1536, 2|4);
    k_gemm_bf16<<<dim3(3,400), 256, 0, stream>>>((const ushort*)SC, f2T, f2b + i*384,
                                                 XT, 1536, 1536, 1536, 384, 1);
  }

  k_fold<<<76800, 256, 0, stream>>>(XT, out);
}

// Round 5
// 2235.364 us; speedup vs baseline: 2.7662x; 1.0948x over previous
//
#include <hip/hip_runtime.h>
#include <hip/hip_bf16.h>
#include <math.h>

// ---------------------------------------------------------------------------
// ConvAttBlock (RegionViT R2L block) — bf16 MFMA GEMMs + MFMA attention.
// B=64, CIN=192, C=384, NH=12, HD=32, HID=1536, WS=7, NB=2.
// Token layout XT: [1024 windows * 50 tokens, 384] fp32 (residual stream).
// ---------------------------------------------------------------------------

typedef __attribute__((ext_vector_type(8))) short short8;   // 8 bf16 (4 VGPR)
typedef __attribute__((ext_vector_type(4))) float f32x4;

__device__ __forceinline__ float gelu_f(float x) {
  return 0.5f * x * (1.0f + erff(x * 0.70710678118654752440f));
}

// ---- LN over 192 channels (NCHW input) + GELU -> channels-last temp --------
__global__ __launch_bounds__(256) void k_ln_gelu_c192(
    const float* __restrict__ x, float* __restrict__ t,
    const float* __restrict__ g, const float* __restrict__ b,
    int HW, int npos)
{
  int wid = threadIdx.x >> 6, lane = threadIdx.x & 63;
  int pos = blockIdx.x * 4 + wid;
  if (pos >= npos) return;
  int bi = pos / HW, p = pos - bi * HW;
  const float* xp = x + (long)bi * 192 * HW + p;
  float v0 = xp[(long)(lane      ) * HW];
  float v1 = xp[(long)(lane +  64) * HW];
  float v2 = xp[(long)(lane + 128) * HW];
  float s  = v0 + v1 + v2;
  float sq = v0*v0 + v1*v1 + v2*v2;
  #pragma unroll
  for (int o = 1; o < 64; o <<= 1) { s += __shfl_xor(s, o); sq += __shfl_xor(sq, o); }
  float mean = s * (1.0f/192.0f);
  float var  = sq * (1.0f/192.0f) - mean*mean;
  float rstd = rsqrtf(var + 1e-5f);
  float* tp = t + (long)pos * 192;
  int c0 = lane, c1 = lane + 64, c2 = lane + 128;
  tp[c0] = gelu_f((v0-mean)*rstd*g[c0] + b[c0]);
  tp[c1] = gelu_f((v1-mean)*rstd*g[c1] + b[c1]);
  tp[c2] = gelu_f((v2-mean)*rstd*g[c2] + b[c2]);
}

// ---- depthwise stride-2 conv (3x3, pad 1, 192->384, 2 out per in chan) -----
__global__ __launch_bounds__(384) void k_dwconv(
    const float* __restrict__ t, const float* __restrict__ w,
    const float* __restrict__ bias, float* __restrict__ XT,
    int Hin, int Win, int Hout, int Wout, int isCls)
{
  int o = threadIdx.x;            // output channel 0..383
  int blk = blockIdx.x;
  int b = blk / Hout, oh = blk - b * Hout;
  int ic = o >> 1;
  float wr[9];
  #pragma unroll
  for (int q = 0; q < 9; ++q) wr[q] = w[q * 384 + o];
  float bo = bias[o];
  const float* tb = t + (long)b * Hin * Win * 192;
  for (int ow = 0; ow < Wout; ++ow) {
    float acc = bo;
    #pragma unroll
    for (int ky = 0; ky < 3; ++ky) {
      int ih = 2*oh - 1 + ky;
      if (ih < 0 || ih >= Hin) continue;
      #pragma unroll
      for (int kx = 0; kx < 3; ++kx) {
        int iw = 2*ow - 1 + kx;
        if (iw < 0 || iw >= Win) continue;
        acc += wr[ky*3+kx] * tb[((long)ih * Win + iw) * 192 + ic];
      }
    }
    int row;
    if (isCls) row = (b * 16 + oh * Wout + ow) * 50;
    else       row = (b * 16 + (oh/7)*4 + (ow/7)) * 50 + 1 + (oh%7)*7 + (ow%7);
    XT[(long)row * 384 + o] = acc;
  }
}

// ---- LayerNorm over C=384, fp32 in (strided rows ok) -> bf16 out -----------
__global__ __launch_bounds__(256) void k_ln384(
    const float* __restrict__ in, long istride,
    __hip_bfloat16* __restrict__ out, long ostride,
    const float* __restrict__ g, const float* __restrict__ b, int rows)
{
  int wid = threadIdx.x >> 6, lane = threadIdx.x & 63;
  int r = blockIdx.x * 4 + wid;
  if (r >= rows) return;
  const float* ip = in + (long)r * istride;
  float x[6]; float s = 0.f, sq = 0.f;
  #pragma unroll
  for (int j = 0; j < 6; ++j) {
    x[j] = ip[lane + 64*j];
    s += x[j]; sq += x[j]*x[j];
  }
  #pragma unroll
  for (int o = 1; o < 64; o <<= 1) { s += __shfl_xor(s, o); sq += __shfl_xor(sq, o); }
  float mean = s * (1.0f/384.0f);
  float var  = sq * (1.0f/384.0f) - mean*mean;
  float rstd = rsqrtf(var + 1e-5f);
  __hip_bfloat16* op = out + (long)r * ostride;
  #pragma unroll
  for (int j = 0; j < 6; ++j) {
    int c = lane + 64*j;
    op[c] = __float2bfloat16((x[j]-mean)*rstd*g[c] + b[c]);
  }
}

// ---- weight transpose + fp32->bf16: W[K][N] -> Wt[N][K] --------------------
__global__ __launch_bounds__(256) void k_wT(
    const float* __restrict__ W, __hip_bfloat16* __restrict__ Wt, int K, int N)
{
  __shared__ ushort t[64][65];
  int n0 = blockIdx.x * 64, k0 = blockIdx.y * 64;
  int c = threadIdx.x & 63, r4 = threadIdx.x >> 6;
  #pragma unroll
  for (int s = 0; s < 16; ++s) {
    int k = r4 + s*4;
    __hip_bfloat16 h = __float2bfloat16(W[(long)(k0+k)*N + n0 + c]);
    t[k][c] = *(ushort*)&h;
  }
  __syncthreads();
  #pragma unroll
  for (int s = 0; s < 16; ++s) {
    int n = r4 + s*4;
    ushort u = t[c][n];
    Wt[(long)(n0+n)*K + k0 + c] = *(__hip_bfloat16*)&u;
  }
}

// ---- bf16 MFMA GEMM: C[M,N] = A[M,K]·Bt[N,K]^T + bias ----------------------
// 128x128 tile, BK=32, 256 thr (4 waves 2x2), mfma_f32_16x16x32_bf16.
// flags: 1=accum into fp32 C, 2=gelu, 4=bf16 output (else fp32)
__global__ __launch_bounds__(256) void k_gemm_bf16(
    const ushort* __restrict__ A, const ushort* __restrict__ Bt,
    const float* __restrict__ bias, void* __restrict__ Cv,
    int K, int lda, int ldbt, int ldc, int flags)
{
  __shared__ ushort As[128*32];
  __shared__ ushort Bs[128*32];
  int tid = threadIdx.x;
  int w = tid >> 6, lane = tid & 63;
  int m0 = blockIdx.y * 128, n0 = blockIdx.x * 128;
  int wr = (w >> 1) * 64, wc = (w & 1) * 64;
  f32x4 acc[4][4] = {};

  int sRow = lane >> 2;            // 0..15 within 16-row chunk
  int sCol = (lane & 3) * 8;       // k element offset (8 bf16 = 16B)
  const ushort* Abase = A  + (long)m0 * lda + sCol;
  const ushort* Bbase = Bt + (long)n0 * ldbt + sCol;

  for (int k0 = 0; k0 < K; k0 += 32) {
    #pragma unroll
    for (int p = 0; p < 2; ++p) {
      int chunk = w + 4*p;             // 0..7, wave-uniform
      int row = chunk * 16 + sRow;
      __builtin_amdgcn_global_load_lds(
        (const __attribute__((address_space(1))) void*)(Abase + (long)row*lda + k0),
        (__attribute__((address_space(3))) void*)(As + chunk*512), 16, 0, 0);
      __builtin_amdgcn_global_load_lds(
        (const __attribute__((address_space(1))) void*)(Bbase + (long)row*ldbt + k0),
        (__attribute__((address_space(3))) void*)(Bs + chunk*512), 16, 0, 0);
    }
    __syncthreads();   // drains vmcnt + lgkmcnt

    short8 af[4], bf[4];
    int kq = (lane >> 4) * 8;
    int fr = lane & 15;
    #pragma unroll
    for (int mi = 0; mi < 4; ++mi)
      af[mi] = *(const short8*)(As + (wr + mi*16 + fr)*32 + kq);
    #pragma unroll
    for (int ni = 0; ni < 4; ++ni)
      bf[ni] = *(const short8*)(Bs + (wc + ni*16 + fr)*32 + kq);
    #pragma unroll
    for (int mi = 0; mi < 4; ++mi)
      #pragma unroll
      for (int ni = 0; ni < 4; ++ni)
        acc[mi][ni] = __builtin_amdgcn_mfma_f32_16x16x32_bf16(af[mi], bf[ni], acc[mi][ni], 0, 0, 0);
    __syncthreads();   // protect LDS before next stage
  }

  // epilogue: C/D layout col=lane&15, row=(lane>>4)*4+reg
  int colq = lane & 15, rowq = (lane >> 4) * 4;
  #pragma unroll
  for (int mi = 0; mi < 4; ++mi) {
    #pragma unroll
    for (int ni = 0; ni < 4; ++ni) {
      int col = n0 + wc + ni*16 + colq;
      float bv = bias[col];
      #pragma unroll
      for (int r = 0; r < 4; ++r) {
        int m = m0 + wr + mi*16 + rowq + r;
        float v = acc[mi][ni][r] + bv;
        if (flags & 2) v = gelu_f(v);
        if (flags & 4) {
          ((__hip_bfloat16*)Cv)[(long)m*ldc + col] = __float2bfloat16(v);
        } else {
          float* Cp = (float*)Cv + (long)m*ldc + col;
          float o = v;
          if (flags & 1) o += *Cp;
          *Cp = o;
        }
      }
    }
  }
}

// ---- MFMA attention: one wave per (group, head) ----------------------------
// NT = token tiles (4 -> N=50 local w/ rel-pos bias, 1 -> N=16 regional).
// qkv bf16 rows [g*N .. g*N+N), cols: q h*32, k 384+h*32, v 768+h*32; out bf16.
template<int NT>
__global__ __launch_bounds__(256) void k_attn3(
    const ushort* __restrict__ qkv, __hip_bfloat16* __restrict__ o,
    const float* __restrict__ relpos, int N, int ld, int ldo)
{
  constexpr int NP   = NT * 16;                 // padded tokens (rows/cols of S)
  constexpr int KTOK = (NP < 32) ? 32 : NP;     // PV K-dim (padded to mfma K)
  constexpr int KS   = 40;                      // Q/K LDS row stride (bf16)
  constexpr int PS   = KTOK + 8;                // P / Vt LDS row stride
  constexpr int QP_ELE = NP * PS;               // Q staged (stride KS), reused for P
  constexpr int K_ELE  = NP * KS;
  constexpr int VT_ELE = 32 * PS;
  constexpr int W_ELE  = QP_ELE + K_ELE + VT_ELE;

  __shared__ __align__(16) ushort lds[4 * W_ELE];
  __shared__ float rpl[4][172];

  int tid = threadIdx.x;
  int w = tid >> 6, lane = tid & 63;
  int head = blockIdx.y * 4 + w;
  int g = blockIdx.x;
  int row0 = g * N;
  const ushort* base = qkv + (long)row0 * ld + head * 32;

  ushort* Ql = lds + w * W_ELE;   // Q (stride KS), later P (stride PS)
  ushort* Kl = Ql + QP_ELE;
  ushort* Vt = Kl + K_ELE;

  // ---- stage Q, K (zero-padded rows), V transposed ----
  for (int e = lane; e < NP * 16; e += 64) {
    int i = e >> 4, c = e & 15;                 // c: ushort2 column
    uint qv = 0, kv = 0;
    if (i < N) {
      const uint* p = (const uint*)(base + (long)i * ld);
      qv = p[c];
      kv = p[c + 192];                          // +384 bf16
    }
    *(uint*)(Ql + i * KS + c * 2) = qv;
    *(uint*)(Kl + i * KS + c * 2) = kv;
  }
  for (int e = lane; e < NP * 32; e += 64) {
    int i = e >> 5, d = e & 31;
    ushort vv = 0;
    if (i < N) vv = base[(long)i * ld + 768 + d];
    Vt[d * PS + i] = vv;
  }
  if constexpr (KTOK > NP) {                    // zero V token-pad cols
    for (int e = lane; e < 32 * (KTOK - NP); e += 64) {
      int d = e / (KTOK - NP), i = NP + e % (KTOK - NP);
      Vt[d * PS + i] = 0;
    }
  }
  if constexpr (NT == 4) {                      // stage rel-pos table
    for (int e = lane; e < 169; e += 64) rpl[w][e] = relpos[head * 169 + e];
  }
  asm volatile("s_waitcnt lgkmcnt(0)" ::: "memory");
  __builtin_amdgcn_sched_barrier(0);

  // ---- QK^T: S[q][k], K=32=HD in one mfma per 16x16 tile ----
  int fr = lane & 15, kq = (lane >> 4) * 8;
  short8 qf[NT], kf[NT];
  #pragma unroll
  for (int mi = 0; mi < NT; ++mi)
    qf[mi] = *(const short8*)(Ql + (mi*16 + fr) * KS + kq);
  #pragma unroll
  for (int ni = 0; ni < NT; ++ni)
    kf[ni] = *(const short8*)(Kl + (ni*16 + fr) * KS + kq);
  f32x4 s[NT][NT] = {};
  #pragma unroll
  for (int mi = 0; mi < NT; ++mi)
    #pragma unroll
    for (int ni = 0; ni < NT; ++ni)
      s[mi][ni] = __builtin_amdgcn_mfma_f32_16x16x32_bf16(qf[mi], kf[ni], s[mi][ni], 0, 0, 0);

  // ---- scale + rel-pos bias + mask + softmax (rows spread over 16 lanes) ----
  const float scale = 0.17677669529663687f;     // 32^-0.5
  int colq = lane & 15, rowq = (lane >> 4) * 4;
  int jv[NT], kr[NT], kc[NT];
  #pragma unroll
  for (int ni = 0; ni < NT; ++ni) {
    jv[ni] = ni*16 + colq;
    int kd = jv[ni] - 1;
    kr[ni] = kd / 7; kc[ni] = kd - kr[ni]*7;    // valid only when 0<jv<N
  }
  #pragma unroll
  for (int mi = 0; mi < NT; ++mi) {
    #pragma unroll
    for (int r = 0; r < 4; ++r) {
      int i = mi*16 + rowq + r;
      float m = -1e30f;
      float sv[NT];
      if constexpr (NT == 4) {
        int qd = i - 1;
        int qr = qd / 7, qc = qd - qr*7;
        #pragma unroll
        for (int ni = 0; ni < NT; ++ni) {
          float v = s[mi][ni][r] * scale;
          if (i > 0 && i < N && jv[ni] > 0 && jv[ni] < N)
            v += rpl[w][(qr - kr[ni] + 6)*13 + (qc - kc[ni] + 6)];
          if (jv[ni] >= N) v = -1e30f;
          sv[ni] = v; m = fmaxf(m, v);
        }
      } else {
        #pragma unroll
        for (int ni = 0; ni < NT; ++ni) { sv[ni] = s[mi][ni][r] * scale; m = fmaxf(m, sv[ni]); }
      }
      #pragma unroll
      for (int o2 = 1; o2 < 16; o2 <<= 1) m = fmaxf(m, __shfl_xor(m, o2));
      float sum = 0.f;
      #pragma unroll
      for (int ni = 0; ni < NT; ++ni) { sv[ni] = __expf(sv[ni] - m); sum += sv[ni]; }
      #pragma unroll
      for (int o2 = 1; o2 < 16; o2 <<= 1) sum += __shfl_xor(sum, o2);
      float rs = 1.0f / sum;
      #pragma unroll
      for (int ni = 0; ni < NT; ++ni) {
        __hip_bfloat16 h = __float2bfloat16(sv[ni] * rs);
        Ql[i * PS + jv[ni]] = *(ushort*)&h;     // P overwrites Q region
      }
    }
  }
  if constexpr (KTOK > NP) {                    // zero P token-pad cols
    for (int e = lane; e < NP * (KTOK - NP); e += 64) {
      int i = e >> 4, j = NP + (e & 15);
      Ql[i * PS + j] = 0;
    }
  }
  asm volatile("s_waitcnt lgkmcnt(0)" ::: "memory");
  __builtin_amdgcn_sched_barrier(0);

  // ---- PV: out[q][d] = P[q][k] · V[k][d], K over KTOK tokens ----
  f32x4 oacc[NT][2] = {};
  #pragma unroll
  for (int ks = 0; ks < KTOK / 32; ++ks) {
    short8 pf[NT];
    #pragma unroll
    for (int mi = 0; mi < NT; ++mi)
      pf[mi] = *(const short8*)(Ql + (mi*16 + fr) * PS + ks*32 + kq);
    #pragma unroll
    for (int di = 0; di < 2; ++di) {
      short8 vf = *(const short8*)(Vt + (di*16 + fr) * PS + ks*32 + kq);
      #pragma unroll
      for (int mi = 0; mi < NT; ++mi)
        oacc[mi][di] = __builtin_amdgcn_mfma_f32_16x16x32_bf16(pf[mi], vf, oacc[mi][di], 0, 0, 0);
    }
  }

  // ---- store (C layout: row=(lane>>4)*4+r, col=lane&15) ----
  #pragma unroll
  for (int mi = 0; mi < NT; ++mi) {
    #pragma unroll
    for (int r = 0; r < 4; ++r) {
      int i = mi*16 + rowq + r;
      if (i < N) {
        __hip_bfloat16* op = o + (long)(row0 + i) * ldo + head * 32;
        #pragma unroll
        for (int di = 0; di < 2; ++di)
          op[di*16 + colq] = __float2bfloat16(oacc[mi][di][r]);
      }
    }
  }
}

// ---- fold token layout back to NCHW outputs --------------------------------
__global__ __launch_bounds__(256) void k_fold(
    const float* __restrict__ XT, float* __restrict__ out)
{
  long idx = (long)blockIdx.x * 256 + threadIdx.x;
  if (idx < 393216) {  // cls_out [64,384,4,4]
    int b = (int)(idx / (384*16));
    int rem = (int)(idx % (384*16));
    int c = rem / 16, p = rem % 16;
    out[idx] = XT[((long)(b*16 + p) * 50) * 384 + c];
  } else {             // patch_out [64,384,28,28]
    long j = idx - 393216;
    int b = (int)(j / (384*784));
    int rem = (int)(j % (384*784));
    int c = rem / 784, p = rem % 784;
    int oh = p / 28, ow = p % 28;
    int row = (b*16 + (oh/7)*4 + ow/7) * 50 + 1 + (oh%7)*7 + (ow%7);
    out[idx] = XT[(long)row * 384 + c];
  }
}

extern "C" void kernel_launch(void* const* d_in, const int* in_sizes, int n_in,
                              void* d_out, int out_size, void* d_ws, size_t ws_size,
                              hipStream_t stream)
{
  const float* cls_in   = (const float*)d_in[0];
  const float* patch_in = (const float*)d_in[1];
  const float* pg   = (const float*)d_in[2];
  const float* pb   = (const float*)d_in[3];
  const float* cw   = (const float*)d_in[4];
  const float* cb   = (const float*)d_in[5];
  const float* n0g  = (const float*)d_in[6];
  const float* n0b  = (const float*)d_in[7];
  const float* n1g  = (const float*)d_in[8];
  const float* n1b  = (const float*)d_in[9];
  const float* n2g  = (const float*)d_in[10];
  const float* n2b  = (const float*)d_in[11];
  const float* qkvw = (const float*)d_in[12];
  const float* qkvb = (const float*)d_in[13];
  const float* apw  = (const float*)d_in[14];
  const float* apb  = (const float*)d_in[15];
  const float* rp   = (const float*)d_in[16];
  const float* f1w  = (const float*)d_in[17];
  const float* f1b  = (const float*)d_in[18];
  const float* f2w  = (const float*)d_in[19];
  const float* f2b  = (const float*)d_in[20];
  float* out = (float*)d_out;

  // workspace (bytes): XT f32 78.6M | LN bf16 39.3M | SC 236M | OB bf16 39.3M | WT bf16 7.1M
  float*          XT = (float*)d_ws;
  __hip_bfloat16* LN = (__hip_bfloat16*)(XT + 19660800);
  float*          SC = (float*)((char*)LN + 39321600);
  __hip_bfloat16* OB = (__hip_bfloat16*)(SC + 58982400);
  __hip_bfloat16* WT = (__hip_bfloat16*)((char*)OB + 39321600);
  float* tP = SC;                 // conv temps alias SC
  float* tC = SC + 38535168;

  // --- projection ---
  k_ln_gelu_c192<<<50176, 256, 0, stream>>>(patch_in, tP, pg, pb, 3136, 200704);
  k_ln_gelu_c192<<<1024,  256, 0, stream>>>(cls_in,   tC, pg, pb, 64,   4096);
  k_dwconv<<<1792, 384, 0, stream>>>(tP, cw, cb, XT, 56, 56, 28, 28, 0);
  k_dwconv<<<256,  384, 0, stream>>>(tC, cw, cb, XT, 8, 8, 4, 4, 1);

  // --- weight transpose/convert (per block: qkvT|apT|fc1T|fc2T) ---
  for (int i = 0; i < 2; ++i) {
    __hip_bfloat16* wb = WT + (long)i * 1769472;
    k_wT<<<dim3(18,6),  256, 0, stream>>>(qkvw + (long)i*442368, wb,           384, 1152);
    k_wT<<<dim3(6,6),   256, 0, stream>>>(apw  + (long)i*147456, wb + 442368,  384, 384);
    k_wT<<<dim3(24,6),  256, 0, stream>>>(f1w  + (long)i*589824, wb + 589824,  384, 1536);
    k_wT<<<dim3(6,24),  256, 0, stream>>>(f2w  + (long)i*589824, wb + 1179648, 1536, 384);
  }

  for (int i = 0; i < 2; ++i) {
    __hip_bfloat16* wb = WT + (long)i * 1769472;
    const ushort* qwT  = (const ushort*)(wb);
    const ushort* apT  = (const ushort*)(wb + 442368);
    const ushort* f1T  = (const ushort*)(wb + 589824);
    const ushort* f2T  = (const ushort*)(wb + 1179648);
    const float* qb  = qkvb + i*1152;
    const float* ab  = apb  + i*384;
    const float* rpi = rp   + (long)i*12*169;

    // regional (cls) attention across 16 windows per image
    k_ln384<<<256, 256, 0, stream>>>(XT, 19200, LN, 384, n0g + i*384, n0b + i*384, 1024);
    k_gemm_bf16<<<dim3(9,8), 256, 0, stream>>>((const ushort*)LN, qwT, qb, SC, 384, 384, 384, 1152, 4);
    k_attn3<1><<<dim3(64,3), 256, 0, stream>>>((const ushort*)SC, OB, (const float*)0, 16, 1152, 384);
    k_gemm_bf16<<<dim3(3,8), 256, 0, stream>>>((const ushort*)OB, apT, ab, XT, 384, 384, 384, 19200, 1);

    // local attention within each window (50 tokens, rel-pos bias)
    k_ln384<<<12800, 256, 0, stream>>>(XT, 384, LN, 384, n1g + i*384, n1b + i*384, 51200);
    k_gemm_bf16<<<dim3(9,400), 256, 0, stream>>>((const ushort*)LN, qwT, qb, SC, 384, 384, 384, 1152, 4);
    k_attn3<4><<<dim3(1024,3), 256, 0, stream>>>((const ushort*)SC, OB, rpi, 50, 1152, 384);
    k_gemm_bf16<<<dim3(3,400), 256, 0, stream>>>((const ushort*)OB, apT, ab, XT, 384, 384, 384, 384, 1);

    // MLP
    k_ln384<<<12800, 256, 0, stream>>>(XT, 384, LN, 384, n2g + i*384, n2b + i*384, 51200);
    k_gemm_bf16<<<dim3(12,400), 256, 0, stream>>>((const ushort*)LN, f1T, f1b + i*1536,
                                                  SC, 384, 384, 384, 1536, 2|4);
    k_gemm_bf16<<<dim3(3,400), 256, 0, stream>>>((const ushort*)SC, f2T, f2b + i*384,
                                                 XT, 1536, 1536, 1536, 384, 1);
  }

  k_fold<<<76800, 256, 0, stream>>>(XT, out);
}

// Round 6
// 2055.544 us; speedup vs baseline: 3.0082x; 1.0875x over previous
//
#include <hip/hip_runtime.h>
#include <hip/hip_bf16.h>
#include <math.h>

// ---------------------------------------------------------------------------
// ConvAttBlock (RegionViT R2L block) — bf16 MFMA GEMMs + MFMA attention
//   + LDS-staged depthwise conv (R6).
// B=64, CIN=192, C=384, NH=12, HD=32, HID=1536, WS=7, NB=2.
// Token layout XT: [1024 windows * 50 tokens, 384] fp32 (residual stream).
// ---------------------------------------------------------------------------

typedef __attribute__((ext_vector_type(8))) short short8;   // 8 bf16 (4 VGPR)
typedef __attribute__((ext_vector_type(4))) float f32x4;
typedef __attribute__((ext_vector_type(8))) ushort ushort8;

__device__ __forceinline__ float gelu_f(float x) {
  return 0.5f * x * (1.0f + erff(x * 0.70710678118654752440f));
}

__device__ __forceinline__ float bf2f(ushort u) {
  union { uint i; float f; } c; c.i = ((uint)u) << 16; return c.f;
}

// ---- LN over 192 channels (NCHW input) + GELU -> channels-last bf16 temp ---
__global__ __launch_bounds__(256) void k_ln_gelu_c192(
    const float* __restrict__ x, __hip_bfloat16* __restrict__ t,
    const float* __restrict__ g, const float* __restrict__ b,
    int HW, int npos)
{
  int wid = threadIdx.x >> 6, lane = threadIdx.x & 63;
  int pos = blockIdx.x * 4 + wid;
  if (pos >= npos) return;
  int bi = pos / HW, p = pos - bi * HW;
  const float* xp = x + (long)bi * 192 * HW + p;
  float v0 = xp[(long)(lane      ) * HW];
  float v1 = xp[(long)(lane +  64) * HW];
  float v2 = xp[(long)(lane + 128) * HW];
  float s  = v0 + v1 + v2;
  float sq = v0*v0 + v1*v1 + v2*v2;
  #pragma unroll
  for (int o = 1; o < 64; o <<= 1) { s += __shfl_xor(s, o); sq += __shfl_xor(sq, o); }
  float mean = s * (1.0f/192.0f);
  float var  = sq * (1.0f/192.0f) - mean*mean;
  float rstd = rsqrtf(var + 1e-5f);
  __hip_bfloat16* tp = t + (long)pos * 192;
  int c0 = lane, c1 = lane + 64, c2 = lane + 128;
  tp[c0] = __float2bfloat16(gelu_f((v0-mean)*rstd*g[c0] + b[c0]));
  tp[c1] = __float2bfloat16(gelu_f((v1-mean)*rstd*g[c1] + b[c1]));
  tp[c2] = __float2bfloat16(gelu_f((v2-mean)*rstd*g[c2] + b[c2]));
}

// ---- depthwise stride-2 conv, LDS-staged (3x3, pad 1, 192->384) ------------
// one block per (image, output row); bf16 channels-last input; fp32 XT out.
template<int WIN>
__global__ __launch_bounds__(384) void k_dwconv2(
    const ushort* __restrict__ t, const float* __restrict__ w,
    const float* __restrict__ bias, float* __restrict__ XT,
    int Hin, int Hout, int Wout, int isCls)
{
  __shared__ ushort lds[3 * WIN * 192];
  int tid = threadIdx.x;
  int blk = blockIdx.x;
  int b = blk / Hout, oh = blk - b * Hout;

  // stage 3 input rows (zero-filled out-of-bounds) with ushort8 loads
  const ushort* tb = t + (long)b * Hin * WIN * 192;
  constexpr int NV = 3 * WIN * 192 / 8;
  for (int v = tid; v < NV; v += 384) {
    int idx = v * 8;
    int r = idx / (WIN * 192);
    int rem = idx - r * (WIN * 192);
    int ih = 2 * oh - 1 + r;
    ushort8 val = {};
    if (ih >= 0 && ih < Hin)
      val = *(const ushort8*)(tb + (long)ih * WIN * 192 + rem);
    *(ushort8*)(lds + idx) = val;
  }
  __syncthreads();

  int o = tid;                    // output channel 0..383
  int ic = o >> 1;
  float wr[9];
  #pragma unroll
  for (int q = 0; q < 9; ++q) wr[q] = w[q * 384 + o];
  float bo = bias[o];

  float carry[3] = {0.f, 0.f, 0.f};   // col 2ow-1 value per row (0 at ow=0)
  for (int ow = 0; ow < Wout; ++ow) {
    float acc = bo;
    #pragma unroll
    for (int r = 0; r < 3; ++r) {
      float a  = carry[r];
      float bI = bf2f(lds[(r * WIN + 2*ow    ) * 192 + ic]);
      float cI = bf2f(lds[(r * WIN + 2*ow + 1) * 192 + ic]);
      acc += a * wr[r*3] + bI * wr[r*3+1] + cI * wr[r*3+2];
      carry[r] = cI;
    }
    int row;
    if (isCls) row = (b * 16 + oh * Wout + ow) * 50;
    else       row = (b * 16 + (oh/7)*4 + (ow/7)) * 50 + 1 + (oh%7)*7 + (ow%7);
    XT[(long)row * 384 + o] = acc;
  }
}

// ---- LayerNorm over C=384, fp32 in (strided rows ok) -> bf16 out -----------
__global__ __launch_bounds__(256) void k_ln384(
    const float* __restrict__ in, long istride,
    __hip_bfloat16* __restrict__ out, long ostride,
    const float* __restrict__ g, const float* __restrict__ b, int rows)
{
  int wid = threadIdx.x >> 6, lane = threadIdx.x & 63;
  int r = blockIdx.x * 4 + wid;
  if (r >= rows) return;
  const float* ip = in + (long)r * istride;
  float x[6]; float s = 0.f, sq = 0.f;
  #pragma unroll
  for (int j = 0; j < 6; ++j) {
    x[j] = ip[lane + 64*j];
    s += x[j]; sq += x[j]*x[j];
  }
  #pragma unroll
  for (int o = 1; o < 64; o <<= 1) { s += __shfl_xor(s, o); sq += __shfl_xor(sq, o); }
  float mean = s * (1.0f/384.0f);
  float var  = sq * (1.0f/384.0f) - mean*mean;
  float rstd = rsqrtf(var + 1e-5f);
  __hip_bfloat16* op = out + (long)r * ostride;
  #pragma unroll
  for (int j = 0; j < 6; ++j) {
    int c = lane + 64*j;
    op[c] = __float2bfloat16((x[j]-mean)*rstd*g[c] + b[c]);
  }
}

// ---- weight transpose + fp32->bf16: W[K][N] -> Wt[N][K] --------------------
__global__ __launch_bounds__(256) void k_wT(
    const float* __restrict__ W, __hip_bfloat16* __restrict__ Wt, int K, int N)
{
  __shared__ ushort t[64][65];
  int n0 = blockIdx.x * 64, k0 = blockIdx.y * 64;
  int c = threadIdx.x & 63, r4 = threadIdx.x >> 6;
  #pragma unroll
  for (int s = 0; s < 16; ++s) {
    int k = r4 + s*4;
    __hip_bfloat16 h = __float2bfloat16(W[(long)(k0+k)*N + n0 + c]);
    t[k][c] = *(ushort*)&h;
  }
  __syncthreads();
  #pragma unroll
  for (int s = 0; s < 16; ++s) {
    int n = r4 + s*4;
    ushort u = t[c][n];
    Wt[(long)(n0+n)*K + k0 + c] = *(__hip_bfloat16*)&u;
  }
}

// ---- bf16 MFMA GEMM: C[M,N] = A[M,K]·Bt[N,K]^T + bias ----------------------
// 128x128 tile, BK=32, 256 thr (4 waves 2x2), mfma_f32_16x16x32_bf16.
// flags: 1=accum into fp32 C, 2=gelu, 4=bf16 output (else fp32)
__global__ __launch_bounds__(256) void k_gemm_bf16(
    const ushort* __restrict__ A, const ushort* __restrict__ Bt,
    const float* __restrict__ bias, void* __restrict__ Cv,
    int K, int lda, int ldbt, int ldc, int flags)
{
  __shared__ ushort As[128*32];
  __shared__ ushort Bs[128*32];
  int tid = threadIdx.x;
  int w = tid >> 6, lane = tid & 63;
  int m0 = blockIdx.y * 128, n0 = blockIdx.x * 128;
  int wr = (w >> 1) * 64, wc = (w & 1) * 64;
  f32x4 acc[4][4] = {};

  int sRow = lane >> 2;            // 0..15 within 16-row chunk
  int sCol = (lane & 3) * 8;       // k element offset (8 bf16 = 16B)
  const ushort* Abase = A  + (long)m0 * lda + sCol;
  const ushort* Bbase = Bt + (long)n0 * ldbt + sCol;

  for (int k0 = 0; k0 < K; k0 += 32) {
    #pragma unroll
    for (int p = 0; p < 2; ++p) {
      int chunk = w + 4*p;             // 0..7, wave-uniform
      int row = chunk * 16 + sRow;
      __builtin_amdgcn_global_load_lds(
        (const __attribute__((address_space(1))) void*)(Abase + (long)row*lda + k0),
        (__attribute__((address_space(3))) void*)(As + chunk*512), 16, 0, 0);
      __builtin_amdgcn_global_load_lds(
        (const __attribute__((address_space(1))) void*)(Bbase + (long)row*ldbt + k0),
        (__attribute__((address_space(3))) void*)(Bs + chunk*512), 16, 0, 0);
    }
    __syncthreads();   // drains vmcnt + lgkmcnt

    short8 af[4], bf[4];
    int kq = (lane >> 4) * 8;
    int fr = lane & 15;
    #pragma unroll
    for (int mi = 0; mi < 4; ++mi)
      af[mi] = *(const short8*)(As + (wr + mi*16 + fr)*32 + kq);
    #pragma unroll
    for (int ni = 0; ni < 4; ++ni)
      bf[ni] = *(const short8*)(Bs + (wc + ni*16 + fr)*32 + kq);
    #pragma unroll
    for (int mi = 0; mi < 4; ++mi)
      #pragma unroll
      for (int ni = 0; ni < 4; ++ni)
        acc[mi][ni] = __builtin_amdgcn_mfma_f32_16x16x32_bf16(af[mi], bf[ni], acc[mi][ni], 0, 0, 0);
    __syncthreads();   // protect LDS before next stage
  }

  // epilogue: C/D layout col=lane&15, row=(lane>>4)*4+reg
  int colq = lane & 15, rowq = (lane >> 4) * 4;
  #pragma unroll
  for (int mi = 0; mi < 4; ++mi) {
    #pragma unroll
    for (int ni = 0; ni < 4; ++ni) {
      int col = n0 + wc + ni*16 + colq;
      float bv = bias[col];
      #pragma unroll
      for (int r = 0; r < 4; ++r) {
        int m = m0 + wr + mi*16 + rowq + r;
        float v = acc[mi][ni][r] + bv;
        if (flags & 2) v = gelu_f(v);
        if (flags & 4) {
          ((__hip_bfloat16*)Cv)[(long)m*ldc + col] = __float2bfloat16(v);
        } else {
          float* Cp = (float*)Cv + (long)m*ldc + col;
          float o = v;
          if (flags & 1) o += *Cp;
          *Cp = o;
        }
      }
    }
  }
}

// ---- MFMA attention: one wave per (group, head) ----------------------------
// NT = token tiles (4 -> N=50 local w/ rel-pos bias, 1 -> N=16 regional).
// qkv bf16 rows [g*N .. g*N+N), cols: q h*32, k 384+h*32, v 768+h*32; out bf16.
template<int NT>
__global__ __launch_bounds__(256) void k_attn3(
    const ushort* __restrict__ qkv, __hip_bfloat16* __restrict__ o,
    const float* __restrict__ relpos, int N, int ld, int ldo)
{
  constexpr int NP   = NT * 16;                 // padded tokens (rows/cols of S)
  constexpr int KTOK = (NP < 32) ? 32 : NP;     // PV K-dim (padded to mfma K)
  constexpr int KS   = 40;                      // Q/K LDS row stride (bf16)
  constexpr int PS   = KTOK + 8;                // P / Vt LDS row stride
  constexpr int QP_ELE = NP * PS;               // Q staged (stride KS), reused for P
  constexpr int K_ELE  = NP * KS;
  constexpr int VT_ELE = 32 * PS;
  constexpr int W_ELE  = QP_ELE + K_ELE + VT_ELE;

  __shared__ __align__(16) ushort lds[4 * W_ELE];
  __shared__ float rpl[4][172];

  int tid = threadIdx.x;
  int w = tid >> 6, lane = tid & 63;
  int head = blockIdx.y * 4 + w;
  int g = blockIdx.x;
  int row0 = g * N;
  const ushort* base = qkv + (long)row0 * ld + head * 32;

  ushort* Ql = lds + w * W_ELE;   // Q (stride KS), later P (stride PS)
  ushort* Kl = Ql + QP_ELE;
  ushort* Vt = Kl + K_ELE;

  // ---- stage Q, K (zero-padded rows), V transposed ----
  for (int e = lane; e < NP * 16; e += 64) {
    int i = e >> 4, c = e & 15;                 // c: ushort2 column
    uint qv = 0, kv = 0;
    if (i < N) {
      const uint* p = (const uint*)(base + (long)i * ld);
      qv = p[c];
      kv = p[c + 192];                          // +384 bf16
    }
    *(uint*)(Ql + i * KS + c * 2) = qv;
    *(uint*)(Kl + i * KS + c * 2) = kv;
  }
  for (int e = lane; e < NP * 32; e += 64) {
    int i = e >> 5, d = e & 31;
    ushort vv = 0;
    if (i < N) vv = base[(long)i * ld + 768 + d];
    Vt[d * PS + i] = vv;
  }
  if constexpr (KTOK > NP) {                    // zero V token-pad cols
    for (int e = lane; e < 32 * (KTOK - NP); e += 64) {
      int d = e / (KTOK - NP), i = NP + e % (KTOK - NP);
      Vt[d * PS + i] = 0;
    }
  }
  if constexpr (NT == 4) {                      // stage rel-pos table
    for (int e = lane; e < 169; e += 64) rpl[w][e] = relpos[head * 169 + e];
  }
  asm volatile("s_waitcnt lgkmcnt(0)" ::: "memory");
  __builtin_amdgcn_sched_barrier(0);

  // ---- QK^T: S[q][k], K=32=HD in one mfma per 16x16 tile ----
  int fr = lane & 15, kq = (lane >> 4) * 8;
  short8 qf[NT], kf[NT];
  #pragma unroll
  for (int mi = 0; mi < NT; ++mi)
    qf[mi] = *(const short8*)(Ql + (mi*16 + fr) * KS + kq);
  #pragma unroll
  for (int ni = 0; ni < NT; ++ni)
    kf[ni] = *(const short8*)(Kl + (ni*16 + fr) * KS + kq);
  f32x4 s[NT][NT] = {};
  #pragma unroll
  for (int mi = 0; mi < NT; ++mi)
    #pragma unroll
    for (int ni = 0; ni < NT; ++ni)
      s[mi][ni] = __builtin_amdgcn_mfma_f32_16x16x32_bf16(qf[mi], kf[ni], s[mi][ni], 0, 0, 0);

  // ---- scale + rel-pos bias + mask + softmax (rows spread over 16 lanes) ----
  const float scale = 0.17677669529663687f;     // 32^-0.5
  int colq = lane & 15, rowq = (lane >> 4) * 4;
  int jv[NT], kr[NT], kc[NT];
  #pragma unroll
  for (int ni = 0; ni < NT; ++ni) {
    jv[ni] = ni*16 + colq;
    int kd = jv[ni] - 1;
    kr[ni] = kd / 7; kc[ni] = kd - kr[ni]*7;    // valid only when 0<jv<N
  }
  #pragma unroll
  for (int mi = 0; mi < NT; ++mi) {
    #pragma unroll
    for (int r = 0; r < 4; ++r) {
      int i = mi*16 + rowq + r;
      float m = -1e30f;
      float sv[NT];
      if constexpr (NT == 4) {
        int qd = i - 1;
        int qr = qd / 7, qc = qd - qr*7;
        #pragma unroll
        for (int ni = 0; ni < NT; ++ni) {
          float v = s[mi][ni][r] * scale;
          if (i > 0 && i < N && jv[ni] > 0 && jv[ni] < N)
            v += rpl[w][(qr - kr[ni] + 6)*13 + (qc - kc[ni] + 6)];
          if (jv[ni] >= N) v = -1e30f;
          sv[ni] = v; m = fmaxf(m, v);
        }
      } else {
        #pragma unroll
        for (int ni = 0; ni < NT; ++ni) { sv[ni] = s[mi][ni][r] * scale; m = fmaxf(m, sv[ni]); }
      }
      #pragma unroll
      for (int o2 = 1; o2 < 16; o2 <<= 1) m = fmaxf(m, __shfl_xor(m, o2));
      float sum = 0.f;
      #pragma unroll
      for (int ni = 0; ni < NT; ++ni) { sv[ni] = __expf(sv[ni] - m); sum += sv[ni]; }
      #pragma unroll
      for (int o2 = 1; o2 < 16; o2 <<= 1) sum += __shfl_xor(sum, o2);
      float rs = 1.0f / sum;
      #pragma unroll
      for (int ni = 0; ni < NT; ++ni) {
        __hip_bfloat16 h = __float2bfloat16(sv[ni] * rs);
        Ql[i * PS + jv[ni]] = *(ushort*)&h;     // P overwrites Q region
      }
    }
  }
  if constexpr (KTOK > NP) {                    // zero P token-pad cols
    for (int e = lane; e < NP * (KTOK - NP); e += 64) {
      int i = e >> 4, j = NP + (e & 15);
      Ql[i * PS + j] = 0;
    }
  }
  asm volatile("s_waitcnt lgkmcnt(0)" ::: "memory");
  __builtin_amdgcn_sched_barrier(0);

  // ---- PV: out[q][d] = P[q][k] · V[k][d], K over KTOK tokens ----
  f32x4 oacc[NT][2] = {};
  #pragma unroll
  for (int ks = 0; ks < KTOK / 32; ++ks) {
    short8 pf[NT];
    #pragma unroll
    for (int mi = 0; mi < NT; ++mi)
      pf[mi] = *(const short8*)(Ql + (mi*16 + fr) * PS + ks*32 + kq);
    #pragma unroll
    for (int di = 0; di < 2; ++di) {
      short8 vf = *(const short8*)(Vt + (di*16 + fr) * PS + ks*32 + kq);
      #pragma unroll
      for (int mi = 0; mi < NT; ++mi)
        oacc[mi][di] = __builtin_amdgcn_mfma_f32_16x16x32_bf16(pf[mi], vf, oacc[mi][di], 0, 0, 0);
    }
  }

  // ---- store (C layout: row=(lane>>4)*4+r, col=lane&15) ----
  #pragma unroll
  for (int mi = 0; mi < NT; ++mi) {
    #pragma unroll
    for (int r = 0; r < 4; ++r) {
      int i = mi*16 + rowq + r;
      if (i < N) {
        __hip_bfloat16* op = o + (long)(row0 + i) * ldo + head * 32;
        #pragma unroll
        for (int di = 0; di < 2; ++di)
          op[di*16 + colq] = __float2bfloat16(oacc[mi][di][r]);
      }
    }
  }
}

// ---- fold token layout back to NCHW outputs --------------------------------
__global__ __launch_bounds__(256) void k_fold(
    const float* __restrict__ XT, float* __restrict__ out)
{
  long idx = (long)blockIdx.x * 256 + threadIdx.x;
  if (idx < 393216) {  // cls_out [64,384,4,4]
    int b = (int)(idx / (384*16));
    int rem = (int)(idx % (384*16));
    int c = rem / 16, p = rem % 16;
    out[idx] = XT[((long)(b*16 + p) * 50) * 384 + c];
  } else {             // patch_out [64,384,28,28]
    long j = idx - 393216;
    int b = (int)(j / (384*784));
    int rem = (int)(j % (384*784));
    int c = rem / 784, p = rem % 784;
    int oh = p / 28, ow = p % 28;
    int row = (b*16 + (oh/7)*4 + ow/7) * 50 + 1 + (oh%7)*7 + (ow%7);
    out[idx] = XT[(long)row * 384 + c];
  }
}

extern "C" void kernel_launch(void* const* d_in, const int* in_sizes, int n_in,
                              void* d_out, int out_size, void* d_ws, size_t ws_size,
                              hipStream_t stream)
{
  const float* cls_in   = (const float*)d_in[0];
  const float* patch_in = (const float*)d_in[1];
  const float* pg   = (const float*)d_in[2];
  const float* pb   = (const float*)d_in[3];
  const float* cw   = (const float*)d_in[4];
  const float* cb   = (const float*)d_in[5];
  const float* n0g  = (const float*)d_in[6];
  const float* n0b  = (const float*)d_in[7];
  const float* n1g  = (const float*)d_in[8];
  const float* n1b  = (const float*)d_in[9];
  const float* n2g  = (const float*)d_in[10];
  const float* n2b  = (const float*)d_in[11];
  const float* qkvw = (const float*)d_in[12];
  const float* qkvb = (const float*)d_in[13];
  const float* apw  = (const float*)d_in[14];
  const float* apb  = (const float*)d_in[15];
  const float* rp   = (const float*)d_in[16];
  const float* f1w  = (const float*)d_in[17];
  const float* f1b  = (const float*)d_in[18];
  const float* f2w  = (const float*)d_in[19];
  const float* f2b  = (const float*)d_in[20];
  float* out = (float*)d_out;

  // workspace (bytes): XT f32 78.6M | LN bf16 39.3M | SC 236M | OB bf16 39.3M | WT bf16 7.1M
  float*          XT = (float*)d_ws;
  __hip_bfloat16* LN = (__hip_bfloat16*)(XT + 19660800);
  float*          SC = (float*)((char*)LN + 39321600);
  __hip_bfloat16* OB = (__hip_bfloat16*)(SC + 58982400);
  __hip_bfloat16* WT = (__hip_bfloat16*)((char*)OB + 39321600);
  __hip_bfloat16* tP = (__hip_bfloat16*)SC;               // conv temps alias SC (bf16 now)
  __hip_bfloat16* tC = tP + (long)64*3136*192;

  // --- projection ---
  k_ln_gelu_c192<<<50176, 256, 0, stream>>>(patch_in, tP, pg, pb, 3136, 200704);
  k_ln_gelu_c192<<<1024,  256, 0, stream>>>(cls_in,   tC, pg, pb, 64,   4096);
  k_dwconv2<56><<<1792, 384, 0, stream>>>((const ushort*)tP, cw, cb, XT, 56, 28, 28, 0);
  k_dwconv2<8> <<<256,  384, 0, stream>>>((const ushort*)tC, cw, cb, XT, 8, 4, 4, 1);

  // --- weight transpose/convert (per block: qkvT|apT|fc1T|fc2T) ---
  for (int i = 0; i < 2; ++i) {
    __hip_bfloat16* wb = WT + (long)i * 1769472;
    k_wT<<<dim3(18,6),  256, 0, stream>>>(qkvw + (long)i*442368, wb,           384, 1152);
    k_wT<<<dim3(6,6),   256, 0, stream>>>(apw  + (long)i*147456, wb + 442368,  384, 384);
    k_wT<<<dim3(24,6),  256, 0, stream>>>(f1w  + (long)i*589824, wb + 589824,  384, 1536);
    k_wT<<<dim3(6,24),  256, 0, stream>>>(f2w  + (long)i*589824, wb + 1179648, 1536, 384);
  }

  for (int i = 0; i < 2; ++i) {
    __hip_bfloat16* wb = WT + (long)i * 1769472;
    const ushort* qwT  = (const ushort*)(wb);
    const ushort* apT  = (const ushort*)(wb + 442368);
    const ushort* f1T  = (const ushort*)(wb + 589824);
    const ushort* f2T  = (const ushort*)(wb + 1179648);
    const float* qb  = qkvb + i*1152;
    const float* ab  = apb  + i*384;
    const float* rpi = rp   + (long)i*12*169;

    // regional (cls) attention across 16 windows per image
    k_ln384<<<256, 256, 0, stream>>>(XT, 19200, LN, 384, n0g + i*384, n0b + i*384, 1024);
    k_gemm_bf16<<<dim3(9,8), 256, 0, stream>>>((const ushort*)LN, qwT, qb, SC, 384, 384, 384, 1152, 4);
    k_attn3<1><<<dim3(64,3), 256, 0, stream>>>((const ushort*)SC, OB, (const float*)0, 16, 1152, 384);
    k_gemm_bf16<<<dim3(3,8), 256, 0, stream>>>((const ushort*)OB, apT, ab, XT, 384, 384, 384, 19200, 1);

    // local attention within each window (50 tokens, rel-pos bias)
    k_ln384<<<12800, 256, 0, stream>>>(XT, 384, LN, 384, n1g + i*384, n1b + i*384, 51200);
    k_gemm_bf16<<<dim3(9,400), 256, 0, stream>>>((const ushort*)LN, qwT, qb, SC, 384, 384, 384, 1152, 4);
    k_attn3<4><<<dim3(1024,3), 256, 0, stream>>>((const ushort*)SC, OB, rpi, 50, 1152, 384);
    k_gemm_bf16<<<dim3(3,400), 256, 0, stream>>>((const ushort*)OB, apT, ab, XT, 384, 384, 384, 384, 1);

    // MLP
    k_ln384<<<12800, 256, 0, stream>>>(XT, 384, LN, 384, n2g + i*384, n2b + i*384, 51200);
    k_gemm_bf16<<<dim3(12,400), 256, 0, stream>>>((const ushort*)LN, f1T, f1b + i*1536,
                                                  SC, 384, 384, 384, 1536, 2|4);
    k_gemm_bf16<<<dim3(3,400), 256, 0, stream>>>((const ushort*)SC, f2T, f2b + i*384,
                                                 XT, 1536, 1536, 1536, 384, 1);
  }

  k_fold<<<76800, 256, 0, stream>>>(XT, out);
}

// Round 7
// 2018.469 us; speedup vs baseline: 3.0635x; 1.0184x over previous
//
#include <hip/hip_runtime.h>
#include <hip/hip_bf16.h>
#include <math.h>

// ---------------------------------------------------------------------------
// ConvAttBlock (RegionViT R2L block) — bf16 MFMA GEMMs + MFMA attention
//   + LDS-staged depthwise conv + transpose-tiled LN192 (R7).
// B=64, CIN=192, C=384, NH=12, HD=32, HID=1536, WS=7, NB=2.
// Token layout XT: [1024 windows * 50 tokens, 384] fp32 (residual stream).
// ---------------------------------------------------------------------------

typedef __attribute__((ext_vector_type(8))) short short8;   // 8 bf16 (4 VGPR)
typedef __attribute__((ext_vector_type(4))) float f32x4;
typedef __attribute__((ext_vector_type(8))) ushort ushort8;

__device__ __forceinline__ float gelu_f(float x) {
  return 0.5f * x * (1.0f + erff(x * 0.70710678118654752440f));
}

__device__ __forceinline__ float bf2f(ushort u) {
  union { uint i; float f; } c; c.i = ((uint)u) << 16; return c.f;
}

// ---- LN over 192 channels + GELU, NCHW -> channels-last bf16 ---------------
// one block = 64 positions x 192 channels of one image; coalesced along HW.
__global__ __launch_bounds__(256) void k_ln_gelu_t(
    const float* __restrict__ x, __hip_bfloat16* __restrict__ t,
    const float* __restrict__ g, const float* __restrict__ b,
    int HW, int nt)   // nt = HW/64
{
  __shared__ float xs[192][65];
  __shared__ float ps[8][64];
  __shared__ float mean_s[64], rstd_s[64];
  int tid = threadIdx.x;
  int bi = blockIdx.x / nt, tile = blockIdx.x % nt;
  const float* xp = x + (long)bi * 192 * HW + tile * 64;

  // load 192x64 fp32, float4 along HW (coalesced)
  for (int v = tid; v < 3072; v += 256) {
    int c = v >> 4;
    int p4 = (v & 15) * 4;
    float4 val = *(const float4*)(xp + (long)c * HW + p4);
    xs[c][p4] = val.x; xs[c][p4+1] = val.y; xs[c][p4+2] = val.z; xs[c][p4+3] = val.w;
  }
  __syncthreads();

  // stats: thread (q = tid>>6, p = tid&63) sums 48 channels
  int p = tid & 63, q = tid >> 6;
  {
    float s = 0.f, sq = 0.f;
    #pragma unroll 8
    for (int j = 0; j < 48; ++j) {
      float v = xs[q*48 + j][p];
      s += v; sq += v*v;
    }
    ps[q][p] = s; ps[4+q][p] = sq;
  }
  __syncthreads();
  if (q == 0) {
    float st  = ps[0][p] + ps[1][p] + ps[2][p] + ps[3][p];
    float sqt = ps[4][p] + ps[5][p] + ps[6][p] + ps[7][p];
    float mean = st * (1.0f/192.0f);
    float var  = sqt * (1.0f/192.0f) - mean*mean;
    mean_s[p] = mean; rstd_s[p] = rsqrtf(var + 1e-5f);
  }
  __syncthreads();

  // output: thread (pos = tid>>2, cblk = (tid&3)*48) writes 48 bf16 contiguous
  int po = tid >> 2, cb = (tid & 3) * 48;
  float mean = mean_s[po], rstd = rstd_s[po];
  __hip_bfloat16* tp = t + ((long)bi * HW + tile * 64 + po) * 192 + cb;
  #pragma unroll
  for (int j8 = 0; j8 < 6; ++j8) {
    ushort8 o8;
    #pragma unroll
    for (int j = 0; j < 8; ++j) {
      int c = cb + j8*8 + j;
      float v = (xs[c][po] - mean) * rstd * g[c] + b[c];
      __hip_bfloat16 h = __float2bfloat16(gelu_f(v));
      o8[j] = *(ushort*)&h;
    }
    *(ushort8*)(tp + j8*8) = o8;
  }
}

// ---- depthwise stride-2 conv, LDS-staged (3x3, pad 1, 192->384) ------------
// one block per (image, output row); bf16 channels-last input; fp32 XT out.
template<int WIN>
__global__ __launch_bounds__(384) void k_dwconv2(
    const ushort* __restrict__ t, const float* __restrict__ w,
    const float* __restrict__ bias, float* __restrict__ XT,
    int Hin, int Hout, int Wout, int isCls)
{
  __shared__ ushort lds[3 * WIN * 192];
  int tid = threadIdx.x;
  int blk = blockIdx.x;
  int b = blk / Hout, oh = blk - b * Hout;

  const ushort* tb = t + (long)b * Hin * WIN * 192;
  constexpr int NV = 3 * WIN * 192 / 8;
  for (int v = tid; v < NV; v += 384) {
    int idx = v * 8;
    int r = idx / (WIN * 192);
    int rem = idx - r * (WIN * 192);
    int ih = 2 * oh - 1 + r;
    ushort8 val = {};
    if (ih >= 0 && ih < Hin)
      val = *(const ushort8*)(tb + (long)ih * WIN * 192 + rem);
    *(ushort8*)(lds + idx) = val;
  }
  __syncthreads();

  int o = tid;
  int ic = o >> 1;
  float wr[9];
  #pragma unroll
  for (int q = 0; q < 9; ++q) wr[q] = w[q * 384 + o];
  float bo = bias[o];

  float carry[3] = {0.f, 0.f, 0.f};
  for (int ow = 0; ow < Wout; ++ow) {
    float acc = bo;
    #pragma unroll
    for (int r = 0; r < 3; ++r) {
      float a  = carry[r];
      float bI = bf2f(lds[(r * WIN + 2*ow    ) * 192 + ic]);
      float cI = bf2f(lds[(r * WIN + 2*ow + 1) * 192 + ic]);
      acc += a * wr[r*3] + bI * wr[r*3+1] + cI * wr[r*3+2];
      carry[r] = cI;
    }
    int row;
    if (isCls) row = (b * 16 + oh * Wout + ow) * 50;
    else       row = (b * 16 + (oh/7)*4 + (ow/7)) * 50 + 1 + (oh%7)*7 + (ow%7);
    XT[(long)row * 384 + o] = acc;
  }
}

// ---- LayerNorm over C=384, fp32 in (strided rows ok) -> bf16 out -----------
__global__ __launch_bounds__(256) void k_ln384(
    const float* __restrict__ in, long istride,
    __hip_bfloat16* __restrict__ out, long ostride,
    const float* __restrict__ g, const float* __restrict__ b, int rows)
{
  int wid = threadIdx.x >> 6, lane = threadIdx.x & 63;
  int r = blockIdx.x * 4 + wid;
  if (r >= rows) return;
  const float* ip = in + (long)r * istride;
  float x[6]; float s = 0.f, sq = 0.f;
  #pragma unroll
  for (int j = 0; j < 6; ++j) {
    x[j] = ip[lane + 64*j];
    s += x[j]; sq += x[j]*x[j];
  }
  #pragma unroll
  for (int o = 1; o < 64; o <<= 1) { s += __shfl_xor(s, o); sq += __shfl_xor(sq, o); }
  float mean = s * (1.0f/384.0f);
  float var  = sq * (1.0f/384.0f) - mean*mean;
  float rstd = rsqrtf(var + 1e-5f);
  __hip_bfloat16* op = out + (long)r * ostride;
  #pragma unroll
  for (int j = 0; j < 6; ++j) {
    int c = lane + 64*j;
    op[c] = __float2bfloat16((x[j]-mean)*rstd*g[c] + b[c]);
  }
}

// ---- weight transpose + fp32->bf16: W[K][N] -> Wt[N][K] --------------------
__global__ __launch_bounds__(256) void k_wT(
    const float* __restrict__ W, __hip_bfloat16* __restrict__ Wt, int K, int N)
{
  __shared__ ushort t[64][65];
  int n0 = blockIdx.x * 64, k0 = blockIdx.y * 64;
  int c = threadIdx.x & 63, r4 = threadIdx.x >> 6;
  #pragma unroll
  for (int s = 0; s < 16; ++s) {
    int k = r4 + s*4;
    __hip_bfloat16 h = __float2bfloat16(W[(long)(k0+k)*N + n0 + c]);
    t[k][c] = *(ushort*)&h;
  }
  __syncthreads();
  #pragma unroll
  for (int s = 0; s < 16; ++s) {
    int n = r4 + s*4;
    ushort u = t[c][n];
    Wt[(long)(n0+n)*K + k0 + c] = *(__hip_bfloat16*)&u;
  }
}

// ---- bf16 MFMA GEMM: C[M,N] = A[M,K]·Bt[N,K]^T + bias ----------------------
// 128x128 tile, BK=32, 256 thr (4 waves 2x2), mfma_f32_16x16x32_bf16.
// flags: 1=accum into fp32 C, 2=gelu, 4=bf16 output (else fp32)
__global__ __launch_bounds__(256) void k_gemm_bf16(
    const ushort* __restrict__ A, const ushort* __restrict__ Bt,
    const float* __restrict__ bias, void* __restrict__ Cv,
    int K, int lda, int ldbt, int ldc, int flags)
{
  __shared__ ushort As[128*32];
  __shared__ ushort Bs[128*32];
  int tid = threadIdx.x;
  int w = tid >> 6, lane = tid & 63;
  int m0 = blockIdx.y * 128, n0 = blockIdx.x * 128;
  int wr = (w >> 1) * 64, wc = (w & 1) * 64;
  f32x4 acc[4][4] = {};

  int sRow = lane >> 2;
  int sCol = (lane & 3) * 8;
  const ushort* Abase = A  + (long)m0 * lda + sCol;
  const ushort* Bbase = Bt + (long)n0 * ldbt + sCol;

  for (int k0 = 0; k0 < K; k0 += 32) {
    #pragma unroll
    for (int p = 0; p < 2; ++p) {
      int chunk = w + 4*p;
      int row = chunk * 16 + sRow;
      __builtin_amdgcn_global_load_lds(
        (const __attribute__((address_space(1))) void*)(Abase + (long)row*lda + k0),
        (__attribute__((address_space(3))) void*)(As + chunk*512), 16, 0, 0);
      __builtin_amdgcn_global_load_lds(
        (const __attribute__((address_space(1))) void*)(Bbase + (long)row*ldbt + k0),
        (__attribute__((address_space(3))) void*)(Bs + chunk*512), 16, 0, 0);
    }
    __syncthreads();

    short8 af[4], bf[4];
    int kq = (lane >> 4) * 8;
    int fr = lane & 15;
    #pragma unroll
    for (int mi = 0; mi < 4; ++mi)
      af[mi] = *(const short8*)(As + (wr + mi*16 + fr)*32 + kq);
    #pragma unroll
    for (int ni = 0; ni < 4; ++ni)
      bf[ni] = *(const short8*)(Bs + (wc + ni*16 + fr)*32 + kq);
    #pragma unroll
    for (int mi = 0; mi < 4; ++mi)
      #pragma unroll
      for (int ni = 0; ni < 4; ++ni)
        acc[mi][ni] = __builtin_amdgcn_mfma_f32_16x16x32_bf16(af[mi], bf[ni], acc[mi][ni], 0, 0, 0);
    __syncthreads();
  }

  int colq = lane & 15, rowq = (lane >> 4) * 4;
  #pragma unroll
  for (int mi = 0; mi < 4; ++mi) {
    #pragma unroll
    for (int ni = 0; ni < 4; ++ni) {
      int col = n0 + wc + ni*16 + colq;
      float bv = bias[col];
      #pragma unroll
      for (int r = 0; r < 4; ++r) {
        int m = m0 + wr + mi*16 + rowq + r;
        float v = acc[mi][ni][r] + bv;
        if (flags & 2) v = gelu_f(v);
        if (flags & 4) {
          ((__hip_bfloat16*)Cv)[(long)m*ldc + col] = __float2bfloat16(v);
        } else {
          float* Cp = (float*)Cv + (long)m*ldc + col;
          float o = v;
          if (flags & 1) o += *Cp;
          *Cp = o;
        }
      }
    }
  }
}

// ---- MFMA attention: one wave per (group, head) ----------------------------
template<int NT>
__global__ __launch_bounds__(256) void k_attn3(
    const ushort* __restrict__ qkv, __hip_bfloat16* __restrict__ o,
    const float* __restrict__ relpos, int N, int ld, int ldo)
{
  constexpr int NP   = NT * 16;
  constexpr int KTOK = (NP < 32) ? 32 : NP;
  constexpr int KS   = 40;
  constexpr int PS   = KTOK + 8;
  constexpr int QP_ELE = NP * PS;
  constexpr int K_ELE  = NP * KS;
  constexpr int VT_ELE = 32 * PS;
  constexpr int W_ELE  = QP_ELE + K_ELE + VT_ELE;

  __shared__ __align__(16) ushort lds[4 * W_ELE];
  __shared__ float rpl[4][172];

  int tid = threadIdx.x;
  int w = tid >> 6, lane = tid & 63;
  int head = blockIdx.y * 4 + w;
  int g = blockIdx.x;
  int row0 = g * N;
  const ushort* base = qkv + (long)row0 * ld + head * 32;

  ushort* Ql = lds + w * W_ELE;
  ushort* Kl = Ql + QP_ELE;
  ushort* Vt = Kl + K_ELE;

  for (int e = lane; e < NP * 16; e += 64) {
    int i = e >> 4, c = e & 15;
    uint qv = 0, kv = 0;
    if (i < N) {
      const uint* p = (const uint*)(base + (long)i * ld);
      qv = p[c];
      kv = p[c + 192];
    }
    *(uint*)(Ql + i * KS + c * 2) = qv;
    *(uint*)(Kl + i * KS + c * 2) = kv;
  }
  for (int e = lane; e < NP * 32; e += 64) {
    int i = e >> 5, d = e & 31;
    ushort vv = 0;
    if (i < N) vv = base[(long)i * ld + 768 + d];
    Vt[d * PS + i] = vv;
  }
  if constexpr (KTOK > NP) {
    for (int e = lane; e < 32 * (KTOK - NP); e += 64) {
      int d = e / (KTOK - NP), i = NP + e % (KTOK - NP);
      Vt[d * PS + i] = 0;
    }
  }
  if constexpr (NT == 4) {
    for (int e = lane; e < 169; e += 64) rpl[w][e] = relpos[head * 169 + e];
  }
  asm volatile("s_waitcnt lgkmcnt(0)" ::: "memory");
  __builtin_amdgcn_sched_barrier(0);

  int fr = lane & 15, kq = (lane >> 4) * 8;
  short8 qf[NT], kf[NT];
  #pragma unroll
  for (int mi = 0; mi < NT; ++mi)
    qf[mi] = *(const short8*)(Ql + (mi*16 + fr) * KS + kq);
  #pragma unroll
  for (int ni = 0; ni < NT; ++ni)
    kf[ni] = *(const short8*)(Kl + (ni*16 + fr) * KS + kq);
  f32x4 s[NT][NT] = {};
  #pragma unroll
  for (int mi = 0; mi < NT; ++mi)
    #pragma unroll
    for (int ni = 0; ni < NT; ++ni)
      s[mi][ni] = __builtin_amdgcn_mfma_f32_16x16x32_bf16(qf[mi], kf[ni], s[mi][ni], 0, 0, 0);

  const float scale = 0.17677669529663687f;
  int colq = lane & 15, rowq = (lane >> 4) * 4;
  int jv[NT], kr[NT], kc[NT];
  #pragma unroll
  for (int ni = 0; ni < NT; ++ni) {
    jv[ni] = ni*16 + colq;
    int kd = jv[ni] - 1;
    kr[ni] = kd / 7; kc[ni] = kd - kr[ni]*7;
  }
  #pragma unroll
  for (int mi = 0; mi < NT; ++mi) {
    #pragma unroll
    for (int r = 0; r < 4; ++r) {
      int i = mi*16 + rowq + r;
      float m = -1e30f;
      float sv[NT];
      if constexpr (NT == 4) {
        int qd = i - 1;
        int qr = qd / 7, qc = qd - qr*7;
        #pragma unroll
        for (int ni = 0; ni < NT; ++ni) {
          float v = s[mi][ni][r] * scale;
          if (i > 0 && i < N && jv[ni] > 0 && jv[ni] < N)
            v += rpl[w][(qr - kr[ni] + 6)*13 + (qc - kc[ni] + 6)];
          if (jv[ni] >= N) v = -1e30f;
          sv[ni] = v; m = fmaxf(m, v);
        }
      } else {
        #pragma unroll
        for (int ni = 0; ni < NT; ++ni) { sv[ni] = s[mi][ni][r] * scale; m = fmaxf(m, sv[ni]); }
      }
      #pragma unroll
      for (int o2 = 1; o2 < 16; o2 <<= 1) m = fmaxf(m, __shfl_xor(m, o2));
      float sum = 0.f;
      #pragma unroll
      for (int ni = 0; ni < NT; ++ni) { sv[ni] = __expf(sv[ni] - m); sum += sv[ni]; }
      #pragma unroll
      for (int o2 = 1; o2 < 16; o2 <<= 1) sum += __shfl_xor(sum, o2);
      float rs = 1.0f / sum;
      #pragma unroll
      for (int ni = 0; ni < NT; ++ni) {
        __hip_bfloat16 h = __float2bfloat16(sv[ni] * rs);
        Ql[i * PS + jv[ni]] = *(ushort*)&h;
      }
    }
  }
  if constexpr (KTOK > NP) {
    for (int e = lane; e < NP * (KTOK - NP); e += 64) {
      int i = e >> 4, j = NP + (e & 15);
      Ql[i * PS + j] = 0;
    }
  }
  asm volatile("s_waitcnt lgkmcnt(0)" ::: "memory");
  __builtin_amdgcn_sched_barrier(0);

  f32x4 oacc[NT][2] = {};
  #pragma unroll
  for (int ks = 0; ks < KTOK / 32; ++ks) {
    short8 pf[NT];
    #pragma unroll
    for (int mi = 0; mi < NT; ++mi)
      pf[mi] = *(const short8*)(Ql + (mi*16 + fr) * PS + ks*32 + kq);
    #pragma unroll
    for (int di = 0; di < 2; ++di) {
      short8 vf = *(const short8*)(Vt + (di*16 + fr) * PS + ks*32 + kq);
      #pragma unroll
      for (int mi = 0; mi < NT; ++mi)
        oacc[mi][di] = __builtin_amdgcn_mfma_f32_16x16x32_bf16(pf[mi], vf, oacc[mi][di], 0, 0, 0);
    }
  }

  #pragma unroll
  for (int mi = 0; mi < NT; ++mi) {
    #pragma unroll
    for (int r = 0; r < 4; ++r) {
      int i = mi*16 + rowq + r;
      if (i < N) {
        __hip_bfloat16* op = o + (long)(row0 + i) * ldo + head * 32;
        #pragma unroll
        for (int di = 0; di < 2; ++di)
          op[di*16 + colq] = __float2bfloat16(oacc[mi][di][r]);
      }
    }
  }
}

// ---- fold token layout back to NCHW outputs --------------------------------
__global__ __launch_bounds__(256) void k_fold(
    const float* __restrict__ XT, float* __restrict__ out)
{
  long idx = (long)blockIdx.x * 256 + threadIdx.x;
  if (idx < 393216) {
    int b = (int)(idx / (384*16));
    int rem = (int)(idx % (384*16));
    int c = rem / 16, p = rem % 16;
    out[idx] = XT[((long)(b*16 + p) * 50) * 384 + c];
  } else {
    long j = idx - 393216;
    int b = (int)(j / (384*784));
    int rem = (int)(j % (384*784));
    int c = rem / 784, p = rem % 784;
    int oh = p / 28, ow = p % 28;
    int row = (b*16 + (oh/7)*4 + ow/7) * 50 + 1 + (oh%7)*7 + (ow%7);
    out[idx] = XT[(long)row * 384 + c];
  }
}

extern "C" void kernel_launch(void* const* d_in, const int* in_sizes, int n_in,
                              void* d_out, int out_size, void* d_ws, size_t ws_size,
                              hipStream_t stream)
{
  const float* cls_in   = (const float*)d_in[0];
  const float* patch_in = (const float*)d_in[1];
  const float* pg   = (const float*)d_in[2];
  const float* pb   = (const float*)d_in[3];
  const float* cw   = (const float*)d_in[4];
  const float* cb   = (const float*)d_in[5];
  const float* n0g  = (const float*)d_in[6];
  const float* n0b  = (const float*)d_in[7];
  const float* n1g  = (const float*)d_in[8];
  const float* n1b  = (const float*)d_in[9];
  const float* n2g  = (const float*)d_in[10];
  const float* n2b  = (const float*)d_in[11];
  const float* qkvw = (const float*)d_in[12];
  const float* qkvb = (const float*)d_in[13];
  const float* apw  = (const float*)d_in[14];
  const float* apb  = (const float*)d_in[15];
  const float* rp   = (const float*)d_in[16];
  const float* f1w  = (const float*)d_in[17];
  const float* f1b  = (const float*)d_in[18];
  const float* f2w  = (const float*)d_in[19];
  const float* f2b  = (const float*)d_in[20];
  float* out = (float*)d_out;

  float*          XT = (float*)d_ws;
  __hip_bfloat16* LN = (__hip_bfloat16*)(XT + 19660800);
  float*          SC = (float*)((char*)LN + 39321600);
  __hip_bfloat16* OB = (__hip_bfloat16*)(SC + 58982400);
  __hip_bfloat16* WT = (__hip_bfloat16*)((char*)OB + 39321600);
  __hip_bfloat16* tP = (__hip_bfloat16*)SC;
  __hip_bfloat16* tC = tP + (long)64*3136*192;

  // --- projection ---
  k_ln_gelu_t<<<64*49, 256, 0, stream>>>(patch_in, tP, pg, pb, 3136, 49);
  k_ln_gelu_t<<<64,    256, 0, stream>>>(cls_in,   tC, pg, pb, 64,   1);
  k_dwconv2<56><<<1792, 384, 0, stream>>>((const ushort*)tP, cw, cb, XT, 56, 28, 28, 0);
  k_dwconv2<8> <<<256,  384, 0, stream>>>((const ushort*)tC, cw, cb, XT, 8, 4, 4, 1);

  // --- weight transpose/convert (per block: qkvT|apT|fc1T|fc2T) ---
  for (int i = 0; i < 2; ++i) {
    __hip_bfloat16* wb = WT + (long)i * 1769472;
    k_wT<<<dim3(18,6),  256, 0, stream>>>(qkvw + (long)i*442368, wb,           384, 1152);
    k_wT<<<dim3(6,6),   256, 0, stream>>>(apw  + (long)i*147456, wb + 442368,  384, 384);
    k_wT<<<dim3(24,6),  256, 0, stream>>>(f1w  + (long)i*589824, wb + 589824,  384, 1536);
    k_wT<<<dim3(6,24),  256, 0, stream>>>(f2w  + (long)i*589824, wb + 1179648, 1536, 384);
  }

  for (int i = 0; i < 2; ++i) {
    __hip_bfloat16* wb = WT + (long)i * 1769472;
    const ushort* qwT  = (const ushort*)(wb);
    const ushort* apT  = (const ushort*)(wb + 442368);
    const ushort* f1T  = (const ushort*)(wb + 589824);
    const ushort* f2T  = (const ushort*)(wb + 1179648);
    const float* qb  = qkvb + i*1152;
    const float* ab  = apb  + i*384;
    const float* rpi = rp   + (long)i*12*169;

    // regional (cls) attention across 16 windows per image
    k_ln384<<<256, 256, 0, stream>>>(XT, 19200, LN, 384, n0g + i*384, n0b + i*384, 1024);
    k_gemm_bf16<<<dim3(9,8), 256, 0, stream>>>((const ushort*)LN, qwT, qb, SC, 384, 384, 384, 1152, 4);
    k_attn3<1><<<dim3(64,3), 256, 0, stream>>>((const ushort*)SC, OB, (const float*)0, 16, 1152, 384);
    k_gemm_bf16<<<dim3(3,8), 256, 0, stream>>>((const ushort*)OB, apT, ab, XT, 384, 384, 384, 19200, 1);

    // local attention within each window (50 tokens, rel-pos bias)
    k_ln384<<<12800, 256, 0, stream>>>(XT, 384, LN, 384, n1g + i*384, n1b + i*384, 51200);
    k_gemm_bf16<<<dim3(9,400), 256, 0, stream>>>((const ushort*)LN, qwT, qb, SC, 384, 384, 384, 1152, 4);
    k_attn3<4><<<dim3(1024,3), 256, 0, stream>>>((const ushort*)SC, OB, rpi, 50, 1152, 384);
    k_gemm_bf16<<<dim3(3,400), 256, 0, stream>>>((const ushort*)OB, apT, ab, XT, 384, 384, 384, 384, 1);

    // MLP
    k_ln384<<<12800, 256, 0, stream>>>(XT, 384, LN, 384, n2g + i*384, n2b + i*384, 51200);
    k_gemm_bf16<<<dim3(12,400), 256, 0, stream>>>((const ushort*)LN, f1T, f1b + i*1536,
                                                  SC, 384, 384, 384, 1536, 2|4);
    k_gemm_bf16<<<dim3(3,400), 256, 0, stream>>>((const ushort*)SC, f2T, f2b + i*384,
                                                 XT, 1536, 1536, 1536, 384, 1);
  }

  k_fold<<<76800, 256, 0, stream>>>(XT, out);
}